// Round 3
// baseline (31582.547 us; speedup 1.0000x reference)
//
#include <hip/hip_runtime.h>
#include <math.h>

// ---------------- ws layout (float offsets), total ~119.3 MiB ----------------
// c3p   [0, 22413312)                      8*96*512*57
// c2ch  [22413312, 28104192)               8*48*130*114 (time-chunk buffer)
// ac    [28104192, 31249920)               4096*768
// A1    [0, 12582912)  (aliases c3p; written after c3p's last read)
// state [31249920, +27648)
#define WS_C3   0u
#define WS_C2CH 22413312u
#define WS_AC   28104192u
#define WS_A1   0u
#define WS_ST   31249920u

__device__ __forceinline__ float sigm(float x){ return 1.0f / (1.0f + expf(-x)); }

// two-level grid barrier: 8 group counters (64B apart) + root, monotonic counts.
// bar = 1-based barrier ordinal (uniform across WGs). 256 WGs, 32 per group.
__device__ __forceinline__ void gbar(unsigned* sy, unsigned bar){
  __syncthreads();
  if (threadIdx.x == 0){
    __threadfence();   // release my WG's stores to agent scope
    unsigned g = blockIdx.x >> 5;
    unsigned v = __hip_atomic_fetch_add(&sy[16 + (g << 4)], 1u,
                                        __ATOMIC_ACQ_REL, __HIP_MEMORY_SCOPE_AGENT);
    if (v == bar*32u - 1u)
      __hip_atomic_fetch_add(&sy[0], 1u,
                             __ATOMIC_ACQ_REL, __HIP_MEMORY_SCOPE_AGENT);
    while (__hip_atomic_load(&sy[0], __ATOMIC_RELAXED, __HIP_MEMORY_SCOPE_AGENT) < bar*8u)
      __builtin_amdgcn_s_sleep(2);
    __threadfence();   // acquire side
  }
  __syncthreads();
}

// ------- conv2f: fused conv1+bn1+relu -> conv2+bn2+relu+pool(1,2), one time row -------
// One block per (b, tt) with tt in [t0-1, t0+127] (130 rows incl. conv3 halo).
// Writes c2ch[b][oc][lt][114], lt = tt-(t0-1). OOB tt rows are written as zeros.
__global__ __launch_bounds__(256) void conv2f_k(
    const float* __restrict__ mel, const float* __restrict__ w1,
    const float* __restrict__ b1, const float* __restrict__ g1,
    const float* __restrict__ be1, const float* __restrict__ m1,
    const float* __restrict__ v1,
    const float* __restrict__ w2, const float* __restrict__ b2,
    const float* __restrict__ g2, const float* __restrict__ be2,
    const float* __restrict__ m2, const float* __restrict__ v2,
    float* __restrict__ c2ch, int t0)
{
  __shared__ float act[3*8*240];     // conv1 output halo, ci-group of 8
  __shared__ float w2s[48*8*12];
  __shared__ float mel5[5*240];
  __shared__ float w1s[48*12];
  __shared__ float sc1[48], sh1[48], sc2[48], sh2[48];
  int tid = threadIdx.x;
  int b = blockIdx.x / 130, lt = blockIdx.x - b*130;
  int t = t0 - 1 + lt;               // conv2 output time row

  int fg = tid % 29, ocg = tid / 29; // valid when tid<232
  int f0 = fg * 8, oc0 = ocg * 6;

  if (t < 0 || t > 511){             // block-uniform: zero-fill OOB halo rows
    if (tid < 232){
      for (int o = 0; o < 6; ++o)
        for (int jj = 0; jj < 4; ++jj){
          int fp = fg*4 + jj;
          if (fp < 114)
            c2ch[((b*48 + oc0 + o)*130 + lt)*114 + fp] = 0.f;
        }
    }
    return;
  }

  // mel halo rows t-2..t+2, col c <-> f = c-2
  for (int idx = tid; idx < 5*240; idx += 256){
    int rr = idx / 240, w = idx - rr*240;
    int tt = t + rr - 2, f = w - 2;
    mel5[idx] = (tt >= 0 && tt < 512 && f >= 0 && f < 229)
                ? mel[(b*512 + tt)*229 + f] : 0.f;
  }
  for (int idx = tid; idx < 48*12; idx += 256){
    int c = idx / 12, q = idx - c*12;
    int kh = q >> 2, kw = q & 3;
    w1s[idx] = (kw < 3) ? w1[c*9 + kh*3 + kw] : 0.f;
  }
  if (tid < 48){
    float s1 = g1[tid] / sqrtf(v1[tid] + 1e-5f);
    sc1[tid] = s1; sh1[tid] = be1[tid] + (b1[tid] - m1[tid]) * s1;
    float s2 = g2[tid] / sqrtf(v2[tid] + 1e-5f);
    sc2[tid] = s2; sh2[tid] = be2[tid] + (b2[tid] - m2[tid]) * s2;
  }

  float acc[6][8];
  #pragma unroll
  for (int o = 0; o < 6; ++o)
    #pragma unroll
    for (int j = 0; j < 8; ++j) acc[o][j] = 0.f;

  for (int ch = 0; ch < 6; ++ch){
    int ci0 = ch * 8;
    __syncthreads();
    // compute conv1 halo for this ci-group on the fly
    for (int idx = tid; idx < 3*8*240; idx += 256){
      int rr = idx / 1920;
      int rem = idx - rr*1920;
      int ci = rem / 240, w = rem - ci*240;
      int tt = t + rr - 1, f = w - 1;   // conv1 output coords
      float val = 0.f;
      if (tt >= 0 && tt < 512 && f >= 0 && f < 229){
        int cg = ci0 + ci;
        float a = 0.f;
        #pragma unroll
        for (int dh = 0; dh < 3; ++dh){
          const float* mr = &mel5[(rr + dh)*240 + w];
          a = fmaf(mr[0], w1s[cg*12 + dh*4 + 0], a);
          a = fmaf(mr[1], w1s[cg*12 + dh*4 + 1], a);
          a = fmaf(mr[2], w1s[cg*12 + dh*4 + 2], a);
        }
        a = a * sc1[cg] + sh1[cg];
        val = a > 0.f ? a : 0.f;
      }
      act[idx] = val;
    }
    for (int idx = tid; idx < 48*8*12; idx += 256){
      int oc = idx / 96;
      int rem = idx - oc*96;
      int ci = rem / 12, q = rem - ci*12;
      int kh = q >> 2, kw = q & 3;
      w2s[idx] = (kw < 3) ? w2[(oc*48 + ci0 + ci)*9 + kh*3 + kw] : 0.f;
    }
    __syncthreads();
    if (tid < 232){
      for (int ci = 0; ci < 8; ++ci){
        #pragma unroll
        for (int kh = 0; kh < 3; ++kh){
          const float* ap = &act[(kh*8 + ci)*240 + f0];
          float4 A0 = *(const float4*)(ap);
          float4 A1v = *(const float4*)(ap + 4);
          float4 A2 = *(const float4*)(ap + 8);
          float L[12] = {A0.x,A0.y,A0.z,A0.w,A1v.x,A1v.y,A1v.z,A1v.w,A2.x,A2.y,A2.z,A2.w};
          #pragma unroll
          for (int o = 0; o < 6; ++o){
            float4 wv = *(const float4*)&w2s[((oc0 + o)*8 + ci)*12 + kh*4];
            #pragma unroll
            for (int j = 0; j < 8; ++j)
              acc[o][j] = fmaf(L[j+2], wv.z, fmaf(L[j+1], wv.y, fmaf(L[j], wv.x, acc[o][j])));
          }
        }
      }
    }
  }
  __syncthreads();
  if (tid < 232){
    #pragma unroll
    for (int o = 0; o < 6; ++o){
      int oc = oc0 + o;
      float s = sc2[oc], hs = sh2[oc];
      #pragma unroll
      for (int jj = 0; jj < 4; ++jj){
        int fp = fg*4 + jj;
        if (fp < 114){
          float v0 = acc[o][2*jj] * s + hs;   v0 = v0 > 0.f ? v0 : 0.f;
          float v1 = acc[o][2*jj+1] * s + hs; v1 = v1 > 0.f ? v1 : 0.f;
          c2ch[((b*48 + oc)*130 + lt)*114 + fp] = v0 > v1 ? v0 : v1;
        }
      }
    }
  }
}

// ------- conv3 (48->96) + bn + relu + pool(1,2), reads chunk buffer -------
__global__ __launch_bounds__(256) void conv3_k(
    const float* __restrict__ c2ch, const float* __restrict__ w3,
    const float* __restrict__ b3, const float* __restrict__ g3,
    const float* __restrict__ be3, const float* __restrict__ m3,
    const float* __restrict__ v3, float* __restrict__ c3p, int t0)
{
  __shared__ float act[3*8*128];
  __shared__ float w3s[96*8*12];
  __shared__ float sc[96], sh[96];
  int tid = threadIdx.x;
  int b = blockIdx.x >> 7, tl = blockIdx.x & 127;
  int t = t0 + tl;
  if (tid < 96){
    float s = g3[tid] / sqrtf(v3[tid] + 1e-5f);
    sc[tid] = s; sh[tid] = be3[tid] + (b3[tid] - m3[tid]) * s;
  }
  int fg = tid % 15, ocg = tid / 15;   // valid when tid<240
  int f0 = fg * 8, oc0 = ocg * 6;
  float acc[6][8];
  #pragma unroll
  for (int o = 0; o < 6; ++o)
    #pragma unroll
    for (int j = 0; j < 8; ++j) acc[o][j] = 0.f;

  for (int ch = 0; ch < 6; ++ch){
    int ci0 = ch * 8;
    __syncthreads();
    for (int idx = tid; idx < 3*8*128; idx += 256){
      int rr = idx >> 10;
      int rem = idx & 1023;
      int ci = rem >> 7, w = rem & 127;
      int lt = tl + rr;                 // c2ch row for time t+rr-1 (always in [0,130))
      int f = w - 1;
      float val = 0.f;
      if (f >= 0 && f < 114)
        val = c2ch[((b*48 + ci0 + ci)*130 + lt)*114 + f];
      act[idx] = val;
    }
    for (int idx = tid; idx < 96*8*12; idx += 256){
      int oc = idx / 96;
      int rem = idx - oc*96;
      int ci = rem / 12, q = rem - ci*12;
      int kh = q >> 2, kw = q & 3;
      w3s[idx] = (kw < 3) ? w3[(oc*48 + ci0 + ci)*9 + kh*3 + kw] : 0.f;
    }
    __syncthreads();
    if (tid < 240){
      for (int ci = 0; ci < 8; ++ci){
        #pragma unroll
        for (int kh = 0; kh < 3; ++kh){
          const float* ap = &act[(kh*8 + ci)*128 + f0];
          float4 A0 = *(const float4*)(ap);
          float4 A1v = *(const float4*)(ap + 4);
          float4 A2 = *(const float4*)(ap + 8);
          float L[12] = {A0.x,A0.y,A0.z,A0.w,A1v.x,A1v.y,A1v.z,A1v.w,A2.x,A2.y,A2.z,A2.w};
          #pragma unroll
          for (int o = 0; o < 6; ++o){
            float4 wv = *(const float4*)&w3s[((oc0 + o)*8 + ci)*12 + kh*4];
            #pragma unroll
            for (int j = 0; j < 8; ++j)
              acc[o][j] = fmaf(L[j+2], wv.z, fmaf(L[j+1], wv.y, fmaf(L[j], wv.x, acc[o][j])));
          }
        }
      }
    }
  }
  __syncthreads();
  if (tid < 240){
    #pragma unroll
    for (int o = 0; o < 6; ++o){
      int oc = oc0 + o;
      float s = sc[oc], hs = sh[oc];
      #pragma unroll
      for (int jj = 0; jj < 4; ++jj){
        int fp = fg*4 + jj;
        if (fp < 57){
          float v0 = acc[o][2*jj] * s + hs;   v0 = v0 > 0.f ? v0 : 0.f;
          float v1 = acc[o][2*jj+1] * s + hs; v1 = v1 > 0.f ? v1 : 0.f;
          c3p[((b*96 + oc)*512 + t)*57 + fp] = v0 > v1 ? v0 : v1;
        }
      }
    }
  }
}

// ------- GEMM: acoustic = conv_feat @ fc_w.T + fc_b  (M=4096,K=5472,N=768) -------
__global__ __launch_bounds__(256) void gemm_fc_k(
    const float* __restrict__ c3p, const float* __restrict__ fcw,
    const float* __restrict__ fcb, float* __restrict__ ac)
{
  __shared__ float As[16*132];
  __shared__ float Bs[16*132];
  int tid = threadIdx.x;
  int m0 = blockIdx.x * 128, n0 = blockIdx.y * 128;
  int tm = (tid & 15) * 8, tn = (tid >> 4) * 8;
  float acc[8][8];
  #pragma unroll
  for (int i = 0; i < 8; ++i)
    #pragma unroll
    for (int j = 0; j < 8; ++j) acc[i][j] = 0.f;

  for (int k0 = 0; k0 < 5472; k0 += 16){
    __syncthreads();
    #pragma unroll
    for (int i = 0; i < 8; ++i){
      int idx = i*256 + tid;
      int k = idx & 15, mm = idx >> 4;
      int gk = k0 + k;
      int ci = (gk * 36793) >> 21;   // /57 magic, exact for gk<2^16
      int f  = gk - ci*57;
      int gm = m0 + mm;
      int bb = gm >> 9, tt = gm & 511;
      As[k*132 + mm] = c3p[((bb*96 + ci)*512 + tt)*57 + f];
      Bs[k*132 + mm] = fcw[(n0 + mm)*5472 + gk];
    }
    __syncthreads();
    #pragma unroll
    for (int k = 0; k < 16; ++k){
      const float* arow = &As[k*132 + tm];
      const float* brow = &Bs[k*132 + tn];
      float4 a0 = *(const float4*)arow, a1 = *(const float4*)(arow + 4);
      float4 b0 = *(const float4*)brow, b1 = *(const float4*)(brow + 4);
      float av[8] = {a0.x,a0.y,a0.z,a0.w,a1.x,a1.y,a1.z,a1.w};
      float bv[8] = {b0.x,b0.y,b0.z,b0.w,b1.x,b1.y,b1.z,b1.w};
      #pragma unroll
      for (int i = 0; i < 8; ++i)
        #pragma unroll
        for (int j = 0; j < 8; ++j)
          acc[i][j] = fmaf(av[i], bv[j], acc[i][j]);
    }
  }
  #pragma unroll
  for (int i = 0; i < 8; ++i){
    int gm = m0 + tm + i;
    #pragma unroll
    for (int j = 0; j < 8; ++j){
      int gn = n0 + tn + j;
      ac[gm*768 + gn] = acc[i][j] + fcb[gn];
    }
  }
}

// ------- GEMM: A1[t][row][b] = acoustic @ wih1[:, :768].T + bih1+bhh1 -------
__global__ __launch_bounds__(256) void gemm_a1_k(
    const float* __restrict__ ac, const float* __restrict__ wih1,
    const float* __restrict__ bih1, const float* __restrict__ bhh1,
    float* __restrict__ A1)
{
  __shared__ float As[16*132];
  __shared__ float Bs[16*132];
  int tid = threadIdx.x;
  int m0 = blockIdx.x * 128, n0 = blockIdx.y * 128;
  int tm = (tid & 15) * 8, tn = (tid >> 4) * 8;
  float acc[8][8];
  #pragma unroll
  for (int i = 0; i < 8; ++i)
    #pragma unroll
    for (int j = 0; j < 8; ++j) acc[i][j] = 0.f;

  for (int k0 = 0; k0 < 768; k0 += 16){
    __syncthreads();
    #pragma unroll
    for (int i = 0; i < 8; ++i){
      int idx = i*256 + tid;
      int k = idx & 15, mm = idx >> 4;
      int gk = k0 + k;
      As[k*132 + mm] = ac[(m0 + mm)*768 + gk];
      Bs[k*132 + mm] = wih1[(n0 + mm)*944 + gk];
    }
    __syncthreads();
    #pragma unroll
    for (int k = 0; k < 16; ++k){
      const float* arow = &As[k*132 + tm];
      const float* brow = &Bs[k*132 + tn];
      float4 a0 = *(const float4*)arow, a1 = *(const float4*)(arow + 4);
      float4 b0 = *(const float4*)brow, b1 = *(const float4*)(brow + 4);
      float av[8] = {a0.x,a0.y,a0.z,a0.w,a1.x,a1.y,a1.z,a1.w};
      float bv[8] = {b0.x,b0.y,b0.z,b0.w,b1.x,b1.y,b1.z,b1.w};
      #pragma unroll
      for (int i = 0; i < 8; ++i)
        #pragma unroll
        for (int j = 0; j < 8; ++j)
          acc[i][j] = fmaf(av[i], bv[j], acc[i][j]);
    }
  }
  #pragma unroll
  for (int i = 0; i < 8; ++i){
    int gm = m0 + tm + i;
    int tt = gm & 511, bb = gm >> 9;
    #pragma unroll
    for (int j = 0; j < 8; ++j){
      int gn = n0 + tn + j;
      A1[tt*24576 + gn*8 + bb] = acc[i][j] + bih1[gn] + bhh1[gn];
    }
  }
}

// ---------------- persistent recurrent kernel ----------------
// 256 WGs x 256 threads, plain launch (NOT hipLaunchCooperativeKernel — that
// API silently refused to launch in this harness; out==stub signature).
// Co-residency: 1 WG/CU guaranteed (4 waves, 43.3KB LDS), 256 WGs on 256 CUs.
// WG wg owns hidden units {3wg..3wg+2} of both LSTMs and (wg<88) pitch wg of
// the post layer. Weights in registers; lanes k-split; LDS reduction;
// 3 grid barriers per time step.
__global__ __launch_bounds__(256, 1) void rec_k(
    const float* __restrict__ A1,
    const float* __restrict__ whh1, const float* __restrict__ wih1,
    const float* __restrict__ wih2, const float* __restrict__ whh2,
    const float* __restrict__ bih2, const float* __restrict__ bhh2,
    const float* __restrict__ postw, const float* __restrict__ postb,
    const float* __restrict__ embw,
    float* __restrict__ xbuf, float* __restrict__ h2b,
    unsigned* __restrict__ sy, float* __restrict__ out)
{
  const int wg = blockIdx.x, tid = threadIdx.x;
  const int wv = tid >> 6, l = tid & 63;
  __shared__ float red[40*268];   // stages A/B use as [96][68]
  __shared__ float zbuf[96];

  float wA[15][3];
  float wB[24][3];
  float wC[3][5];
  {
    int Rb = wv*768 + wg*3;
    #pragma unroll
    for (int ki = 0; ki < 15; ++ki){
      int k = l + (ki << 6);
      #pragma unroll
      for (int u = 0; u < 3; ++u){
        float w = 0.f;
        if (k < 768) w = whh1[(Rb + u)*768 + k];
        else if (k < 944) w = wih1[(Rb + u)*944 + k];
        wA[ki][u] = w;
      }
    }
    #pragma unroll
    for (int ki = 0; ki < 24; ++ki){
      int k = l + (ki << 6);
      #pragma unroll
      for (int u = 0; u < 3; ++u)
        wB[ki][u] = (k < 768) ? wih2[(Rb + u)*768 + k] : whh2[(Rb + u)*768 + k - 768];
    }
  }
  if (wg < 88){
    #pragma unroll
    for (int kc = 0; kc < 3; ++kc)
      #pragma unroll
      for (int s = 0; s < 5; ++s)
        wC[kc][s] = postw[(wg*5 + s)*768 + tid + (kc << 8)];
  }
  float b2r = 0.f; int fR = 0, fb = 0;
  if (tid < 96){
    int g = tid / 24, rem = tid - g*24;
    int u = rem >> 3; fb = rem & 7;
    fR = g*768 + wg*3 + u;
    b2r = bih2[fR] + bhh2[fR];
  }
  float pbr = (wg < 88 && tid < 40) ? postb[wg*5 + (tid >> 3)] : 0.f;
  float c1r = 0.f, c2r = 0.f;

  if (wg == 0){
    for (int idx = tid; idx < 1408; idx += 256){
      int e = idx >> 3, bb = idx & 7;
      xbuf[(768 + e)*8 + bb] = embw[e & 1];   // emb(prev=0) for step 0
    }
  }
  unsigned bar = 1;
  gbar(sy, bar);

  for (int t = 0; t < 512; ++t){
    const int cur = t & 1, nxt = cur ^ 1;
    float* xc  = xbuf + cur * 7552;
    float* xn  = xbuf + nxt * 7552;
    float* h2c = h2b + cur * 6144;
    float* h2n = h2b + nxt * 6144;

    // ---- stage A: gates1 = A1[t] + [h1,emb] @ [whh1|We].T ; cell1 ----
    {
      float acc[3][8];
      #pragma unroll
      for (int u = 0; u < 3; ++u)
        #pragma unroll
        for (int j = 0; j < 8; ++j) acc[u][j] = 0.f;
      #pragma unroll
      for (int ki = 0; ki < 15; ++ki){
        int k = l + (ki << 6);
        if (k < 944){
          const float4* xp = (const float4*)(xc + k*8);
          float4 x0 = xp[0], x1 = xp[1];
          #pragma unroll
          for (int u = 0; u < 3; ++u){
            float w = wA[ki][u];
            acc[u][0] = fmaf(w, x0.x, acc[u][0]);
            acc[u][1] = fmaf(w, x0.y, acc[u][1]);
            acc[u][2] = fmaf(w, x0.z, acc[u][2]);
            acc[u][3] = fmaf(w, x0.w, acc[u][3]);
            acc[u][4] = fmaf(w, x1.x, acc[u][4]);
            acc[u][5] = fmaf(w, x1.y, acc[u][5]);
            acc[u][6] = fmaf(w, x1.z, acc[u][6]);
            acc[u][7] = fmaf(w, x1.w, acc[u][7]);
          }
        }
      }
      #pragma unroll
      for (int u = 0; u < 3; ++u)
        #pragma unroll
        for (int j = 0; j < 8; ++j)
          red[(wv*24 + u*8 + j)*68 + l] = acc[u][j];
      __syncthreads();
      if (tid < 96){
        const float4* rp = (const float4*)(red + tid*68);
        float sum = 0.f;
        #pragma unroll
        for (int q = 0; q < 16; ++q){
          float4 r4 = rp[q];
          sum += (r4.x + r4.y) + (r4.z + r4.w);
        }
        sum += A1[t*24576 + fR*8 + fb];
        zbuf[tid] = sum;
      }
      __syncthreads();
      if (tid < 24){
        float zi = zbuf[tid], zf = zbuf[24 + tid], zg = zbuf[48 + tid], zo = zbuf[72 + tid];
        c1r = sigm(zf)*c1r + sigm(zi)*tanhf(zg);
        float hh = sigm(zo)*tanhf(c1r);
        xn[(wg*3 + (tid >> 3))*8 + (tid & 7)] = hh;
      }
      ++bar; gbar(sy, bar);
    }

    // ---- stage B: gates2 = h1n @ wih2.T + h2 @ whh2.T + b ; cell2 ----
    {
      float acc[3][8];
      #pragma unroll
      for (int u = 0; u < 3; ++u)
        #pragma unroll
        for (int j = 0; j < 8; ++j) acc[u][j] = 0.f;
      #pragma unroll
      for (int ki = 0; ki < 24; ++ki){
        int k = l + (ki << 6);
        const float* src = (ki < 12) ? (xn + k*8) : (h2c + (k - 768)*8);
        float4 x0 = ((const float4*)src)[0];
        float4 x1 = ((const float4*)src)[1];
        #pragma unroll
        for (int u = 0; u < 3; ++u){
          float w = wB[ki][u];
          acc[u][0] = fmaf(w, x0.x, acc[u][0]);
          acc[u][1] = fmaf(w, x0.y, acc[u][1]);
          acc[u][2] = fmaf(w, x0.z, acc[u][2]);
          acc[u][3] = fmaf(w, x0.w, acc[u][3]);
          acc[u][4] = fmaf(w, x1.x, acc[u][4]);
          acc[u][5] = fmaf(w, x1.y, acc[u][5]);
          acc[u][6] = fmaf(w, x1.z, acc[u][6]);
          acc[u][7] = fmaf(w, x1.w, acc[u][7]);
        }
      }
      #pragma unroll
      for (int u = 0; u < 3; ++u)
        #pragma unroll
        for (int j = 0; j < 8; ++j)
          red[(wv*24 + u*8 + j)*68 + l] = acc[u][j];
      __syncthreads();
      if (tid < 96){
        const float4* rp = (const float4*)(red + tid*68);
        float sum = 0.f;
        #pragma unroll
        for (int q = 0; q < 16; ++q){
          float4 r4 = rp[q];
          sum += (r4.x + r4.y) + (r4.z + r4.w);
        }
        sum += b2r;
        zbuf[tid] = sum;
      }
      __syncthreads();
      if (tid < 24){
        float zi = zbuf[tid], zf = zbuf[24 + tid], zg = zbuf[48 + tid], zo = zbuf[72 + tid];
        c2r = sigm(zf)*c2r + sigm(zi)*tanhf(zg);
        float hh = sigm(zo)*tanhf(c2r);
        h2n[(wg*3 + (tid >> 3))*8 + (tid & 7)] = hh;
      }
      ++bar; gbar(sy, bar);
    }

    // ---- stage C: logits for pitch wg; argmax -> emb for next step ----
    if (wg < 88){
      float acc[5][8];
      #pragma unroll
      for (int s = 0; s < 5; ++s)
        #pragma unroll
        for (int j = 0; j < 8; ++j) acc[s][j] = 0.f;
      #pragma unroll
      for (int kc = 0; kc < 3; ++kc){
        int k = tid + (kc << 8);
        const float4* xp = (const float4*)(h2n + k*8);
        float4 x0 = xp[0], x1 = xp[1];
        #pragma unroll
        for (int s = 0; s < 5; ++s){
          float w = wC[kc][s];
          acc[s][0] = fmaf(w, x0.x, acc[s][0]);
          acc[s][1] = fmaf(w, x0.y, acc[s][1]);
          acc[s][2] = fmaf(w, x0.z, acc[s][2]);
          acc[s][3] = fmaf(w, x0.w, acc[s][3]);
          acc[s][4] = fmaf(w, x1.x, acc[s][4]);
          acc[s][5] = fmaf(w, x1.y, acc[s][5]);
          acc[s][6] = fmaf(w, x1.z, acc[s][6]);
          acc[s][7] = fmaf(w, x1.w, acc[s][7]);
        }
      }
      #pragma unroll
      for (int s = 0; s < 5; ++s)
        #pragma unroll
        for (int j = 0; j < 8; ++j)
          red[(s*8 + j)*268 + tid] = acc[s][j];
      __syncthreads();
      if (tid < 40){
        const float4* rp = (const float4*)(red + tid*268);
        float sum = 0.f;
        #pragma unroll
        for (int q = 0; q < 64; ++q){
          float4 r4 = rp[q];
          sum += (r4.x + r4.y) + (r4.z + r4.w);
        }
        sum += pbr;
        int s = tid >> 3, bb = tid & 7;
        out[bb*225280 + t*440 + wg*5 + s] = sum;
        zbuf[tid] = sum;
      }
      __syncthreads();
      if (tid < 8){
        float best = zbuf[tid]; int bs = 0;
        #pragma unroll
        for (int s = 1; s < 5; ++s){
          float v = zbuf[s*8 + tid];
          if (v > best){ best = v; bs = s; }   // first max wins (jnp.argmax)
        }
        xn[(768 + wg*2)*8 + tid]     = embw[bs*2];
        xn[(768 + wg*2 + 1)*8 + tid] = embw[bs*2 + 1];
      }
    }
    ++bar; gbar(sy, bar);
  }
}

extern "C" void kernel_launch(void* const* d_in, const int* in_sizes, int n_in,
                              void* d_out, int out_size, void* d_ws, size_t ws_size,
                              hipStream_t stream)
{
  (void)in_sizes; (void)n_in; (void)out_size; (void)ws_size;
  const float* mel  = (const float*)d_in[0];
  const float* w1   = (const float*)d_in[1];
  const float* b1   = (const float*)d_in[2];
  const float* g1   = (const float*)d_in[3];
  const float* be1  = (const float*)d_in[4];
  const float* m1   = (const float*)d_in[5];
  const float* v1   = (const float*)d_in[6];
  const float* w2   = (const float*)d_in[7];
  const float* b2   = (const float*)d_in[8];
  const float* g2   = (const float*)d_in[9];
  const float* be2  = (const float*)d_in[10];
  const float* m2   = (const float*)d_in[11];
  const float* v2   = (const float*)d_in[12];
  const float* w3   = (const float*)d_in[13];
  const float* b3   = (const float*)d_in[14];
  const float* g3   = (const float*)d_in[15];
  const float* be3  = (const float*)d_in[16];
  const float* m3   = (const float*)d_in[17];
  const float* v3   = (const float*)d_in[18];
  const float* fcw  = (const float*)d_in[19];
  const float* fcb  = (const float*)d_in[20];
  const float* wih1 = (const float*)d_in[21];
  const float* whh1 = (const float*)d_in[22];
  const float* bih1 = (const float*)d_in[23];
  const float* bhh1 = (const float*)d_in[24];
  const float* wih2 = (const float*)d_in[25];
  const float* whh2 = (const float*)d_in[26];
  const float* bih2 = (const float*)d_in[27];
  const float* bhh2 = (const float*)d_in[28];
  const float* postw= (const float*)d_in[29];
  const float* postb= (const float*)d_in[30];
  const float* embw = (const float*)d_in[31];

  float* ws    = (float*)d_ws;
  float* c3p   = ws + WS_C3;
  float* c2ch  = ws + WS_C2CH;
  float* ac    = ws + WS_AC;
  float* A1    = ws + WS_A1;
  float* st    = ws + WS_ST;
  float* xbuf  = st;
  float* h2b   = st + 15104;
  unsigned* sy = (unsigned*)(st + 27392);
  float* outp  = (float*)d_out;

  // zero recurrent state + barrier counters (ws is re-poisoned before each launch)
  hipMemsetAsync(st, 0, 27648 * sizeof(float), stream);

  // conv stack, time-chunked (4 chunks of 128), chunk dependency via stream order
  for (int c = 0; c < 4; ++c){
    int t0 = c * 128;
    conv2f_k<<<dim3(8*130), dim3(256), 0, stream>>>(
        mel, w1, b1, g1, be1, m1, v1, w2, b2, g2, be2, m2, v2, c2ch, t0);
    conv3_k<<<dim3(8*128), dim3(256), 0, stream>>>(
        c2ch, w3, b3, g3, be3, m3, v3, c3p, t0);
  }
  gemm_fc_k<<<dim3(32, 6), dim3(256), 0, stream>>>(c3p, fcw, fcb, ac);
  gemm_a1_k<<<dim3(32, 24), dim3(256), 0, stream>>>(ac, wih1, bih1, bhh1, A1);

  // plain launch: 256 WGs co-resident by construction (1 WG/CU resources)
  rec_k<<<dim3(256), dim3(256), 0, stream>>>(
      A1, whh1, wih1, wih2, whh2, bih2, bhh2, postw, postb, embw,
      xbuf, h2b, sy, outp);
}

// Round 4
// 29054.144 us; speedup vs baseline: 1.0870x; 1.0870x over previous
//
#include <hip/hip_runtime.h>
#include <math.h>

// ---------------- ws layout (float offsets), total ~119.3 MiB ----------------
// c3p   [0, 22413312)                      8*96*512*57
// c2ch  [22413312, 28104192)               8*48*130*114 (time-chunk buffer)
// ac    [28104192, 31249920)               4096*768
// A1    [0, 12582912)  (aliases c3p; written after c3p's last read)
// state [31249920, +27648)
#define WS_C3   0u
#define WS_C2CH 22413312u
#define WS_AC   28104192u
#define WS_A1   0u
#define WS_ST   31249920u

__device__ __forceinline__ float sigm(float x){ return 1.0f / (1.0f + expf(-x)); }

// Fine-grained coherent access: system-scope relaxed atomics compile to
// cache-bypassing (sc0 sc1) loads/stores served at the Infinity-Cache
// coherence point — visible across XCDs WITHOUT any L2 writeback/invalidate.
__device__ __forceinline__ float cload(const float* p){
  unsigned u = __hip_atomic_load((const unsigned*)p, __ATOMIC_RELAXED,
                                 __HIP_MEMORY_SCOPE_SYSTEM);
  union { unsigned u; float f; } c; c.u = u; return c.f;
}
__device__ __forceinline__ void cstore(float* p, float v){
  union { float f; unsigned u; } c; c.f = v;
  __hip_atomic_store((unsigned*)p, c.u, __ATOMIC_RELAXED,
                     __HIP_MEMORY_SCOPE_SYSTEM);
}

// two-level grid barrier: 8 group counters (64B apart) + root, monotonic counts.
// NO __threadfence: all cross-WG data uses coherent (sc0sc1) access, and the
// compiler's vmcnt(0)-drain before s_barrier (entry __syncthreads) guarantees
// those write-through stores are globally visible before the counter bump.
__device__ __forceinline__ void gbar(unsigned* sy, unsigned bar){
  __syncthreads();   // drains vmcnt(0): all lanes' coherent stores are visible
  if (threadIdx.x == 0){
    unsigned g = blockIdx.x >> 5;
    unsigned v = __hip_atomic_fetch_add(&sy[16 + (g << 4)], 1u,
                                        __ATOMIC_RELAXED, __HIP_MEMORY_SCOPE_SYSTEM);
    if (v == bar*32u - 1u)
      __hip_atomic_fetch_add(&sy[0], 1u,
                             __ATOMIC_RELAXED, __HIP_MEMORY_SCOPE_SYSTEM);
    while (__hip_atomic_load(&sy[0], __ATOMIC_RELAXED, __HIP_MEMORY_SCOPE_SYSTEM) < bar*8u)
      __builtin_amdgcn_s_sleep(2);
  }
  __syncthreads();
}

// ------- conv2f: fused conv1+bn1+relu -> conv2+bn2+relu+pool(1,2), one time row -------
__global__ __launch_bounds__(256) void conv2f_k(
    const float* __restrict__ mel, const float* __restrict__ w1,
    const float* __restrict__ b1, const float* __restrict__ g1,
    const float* __restrict__ be1, const float* __restrict__ m1,
    const float* __restrict__ v1,
    const float* __restrict__ w2, const float* __restrict__ b2,
    const float* __restrict__ g2, const float* __restrict__ be2,
    const float* __restrict__ m2, const float* __restrict__ v2,
    float* __restrict__ c2ch, int t0)
{
  __shared__ float act[3*8*240];     // conv1 output halo, ci-group of 8
  __shared__ float w2s[48*8*12];
  __shared__ float mel5[5*240];
  __shared__ float w1s[48*12];
  __shared__ float sc1[48], sh1[48], sc2[48], sh2[48];
  int tid = threadIdx.x;
  int b = blockIdx.x / 130, lt = blockIdx.x - b*130;
  int t = t0 - 1 + lt;               // conv2 output time row

  int fg = tid % 29, ocg = tid / 29; // valid when tid<232
  int f0 = fg * 8, oc0 = ocg * 6;

  if (t < 0 || t > 511){             // block-uniform: zero-fill OOB halo rows
    if (tid < 232){
      for (int o = 0; o < 6; ++o)
        for (int jj = 0; jj < 4; ++jj){
          int fp = fg*4 + jj;
          if (fp < 114)
            c2ch[((b*48 + oc0 + o)*130 + lt)*114 + fp] = 0.f;
        }
    }
    return;
  }

  for (int idx = tid; idx < 5*240; idx += 256){
    int rr = idx / 240, w = idx - rr*240;
    int tt = t + rr - 2, f = w - 2;
    mel5[idx] = (tt >= 0 && tt < 512 && f >= 0 && f < 229)
                ? mel[(b*512 + tt)*229 + f] : 0.f;
  }
  for (int idx = tid; idx < 48*12; idx += 256){
    int c = idx / 12, q = idx - c*12;
    int kh = q >> 2, kw = q & 3;
    w1s[idx] = (kw < 3) ? w1[c*9 + kh*3 + kw] : 0.f;
  }
  if (tid < 48){
    float s1 = g1[tid] / sqrtf(v1[tid] + 1e-5f);
    sc1[tid] = s1; sh1[tid] = be1[tid] + (b1[tid] - m1[tid]) * s1;
    float s2 = g2[tid] / sqrtf(v2[tid] + 1e-5f);
    sc2[tid] = s2; sh2[tid] = be2[tid] + (b2[tid] - m2[tid]) * s2;
  }

  float acc[6][8];
  #pragma unroll
  for (int o = 0; o < 6; ++o)
    #pragma unroll
    for (int j = 0; j < 8; ++j) acc[o][j] = 0.f;

  for (int ch = 0; ch < 6; ++ch){
    int ci0 = ch * 8;
    __syncthreads();
    for (int idx = tid; idx < 3*8*240; idx += 256){
      int rr = idx / 1920;
      int rem = idx - rr*1920;
      int ci = rem / 240, w = rem - ci*240;
      int tt = t + rr - 1, f = w - 1;   // conv1 output coords
      float val = 0.f;
      if (tt >= 0 && tt < 512 && f >= 0 && f < 229){
        int cg = ci0 + ci;
        float a = 0.f;
        #pragma unroll
        for (int dh = 0; dh < 3; ++dh){
          const float* mr = &mel5[(rr + dh)*240 + w];
          a = fmaf(mr[0], w1s[cg*12 + dh*4 + 0], a);
          a = fmaf(mr[1], w1s[cg*12 + dh*4 + 1], a);
          a = fmaf(mr[2], w1s[cg*12 + dh*4 + 2], a);
        }
        a = a * sc1[cg] + sh1[cg];
        val = a > 0.f ? a : 0.f;
      }
      act[idx] = val;
    }
    for (int idx = tid; idx < 48*8*12; idx += 256){
      int oc = idx / 96;
      int rem = idx - oc*96;
      int ci = rem / 12, q = rem - ci*12;
      int kh = q >> 2, kw = q & 3;
      w2s[idx] = (kw < 3) ? w2[(oc*48 + ci0 + ci)*9 + kh*3 + kw] : 0.f;
    }
    __syncthreads();
    if (tid < 232){
      for (int ci = 0; ci < 8; ++ci){
        #pragma unroll
        for (int kh = 0; kh < 3; ++kh){
          const float* ap = &act[(kh*8 + ci)*240 + f0];
          float4 A0 = *(const float4*)(ap);
          float4 A1v = *(const float4*)(ap + 4);
          float4 A2 = *(const float4*)(ap + 8);
          float L[12] = {A0.x,A0.y,A0.z,A0.w,A1v.x,A1v.y,A1v.z,A1v.w,A2.x,A2.y,A2.z,A2.w};
          #pragma unroll
          for (int o = 0; o < 6; ++o){
            float4 wv = *(const float4*)&w2s[((oc0 + o)*8 + ci)*12 + kh*4];
            #pragma unroll
            for (int j = 0; j < 8; ++j)
              acc[o][j] = fmaf(L[j+2], wv.z, fmaf(L[j+1], wv.y, fmaf(L[j], wv.x, acc[o][j])));
          }
        }
      }
    }
  }
  __syncthreads();
  if (tid < 232){
    #pragma unroll
    for (int o = 0; o < 6; ++o){
      int oc = oc0 + o;
      float s = sc2[oc], hs = sh2[oc];
      #pragma unroll
      for (int jj = 0; jj < 4; ++jj){
        int fp = fg*4 + jj;
        if (fp < 114){
          float v0 = acc[o][2*jj] * s + hs;   v0 = v0 > 0.f ? v0 : 0.f;
          float v1 = acc[o][2*jj+1] * s + hs; v1 = v1 > 0.f ? v1 : 0.f;
          c2ch[((b*48 + oc)*130 + lt)*114 + fp] = v0 > v1 ? v0 : v1;
        }
      }
    }
  }
}

// ------- conv3 (48->96) + bn + relu + pool(1,2), reads chunk buffer -------
__global__ __launch_bounds__(256) void conv3_k(
    const float* __restrict__ c2ch, const float* __restrict__ w3,
    const float* __restrict__ b3, const float* __restrict__ g3,
    const float* __restrict__ be3, const float* __restrict__ m3,
    const float* __restrict__ v3, float* __restrict__ c3p, int t0)
{
  __shared__ float act[3*8*128];
  __shared__ float w3s[96*8*12];
  __shared__ float sc[96], sh[96];
  int tid = threadIdx.x;
  int b = blockIdx.x >> 7, tl = blockIdx.x & 127;
  int t = t0 + tl;
  if (tid < 96){
    float s = g3[tid] / sqrtf(v3[tid] + 1e-5f);
    sc[tid] = s; sh[tid] = be3[tid] + (b3[tid] - m3[tid]) * s;
  }
  int fg = tid % 15, ocg = tid / 15;   // valid when tid<240
  int f0 = fg * 8, oc0 = ocg * 6;
  float acc[6][8];
  #pragma unroll
  for (int o = 0; o < 6; ++o)
    #pragma unroll
    for (int j = 0; j < 8; ++j) acc[o][j] = 0.f;

  for (int ch = 0; ch < 6; ++ch){
    int ci0 = ch * 8;
    __syncthreads();
    for (int idx = tid; idx < 3*8*128; idx += 256){
      int rr = idx >> 10;
      int rem = idx & 1023;
      int ci = rem >> 7, w = rem & 127;
      int lt = tl + rr;                 // c2ch row for time t+rr-1 (always in [0,130))
      int f = w - 1;
      float val = 0.f;
      if (f >= 0 && f < 114)
        val = c2ch[((b*48 + ci0 + ci)*130 + lt)*114 + f];
      act[idx] = val;
    }
    for (int idx = tid; idx < 96*8*12; idx += 256){
      int oc = idx / 96;
      int rem = idx - oc*96;
      int ci = rem / 12, q = rem - ci*12;
      int kh = q >> 2, kw = q & 3;
      w3s[idx] = (kw < 3) ? w3[(oc*48 + ci0 + ci)*9 + kh*3 + kw] : 0.f;
    }
    __syncthreads();
    if (tid < 240){
      for (int ci = 0; ci < 8; ++ci){
        #pragma unroll
        for (int kh = 0; kh < 3; ++kh){
          const float* ap = &act[(kh*8 + ci)*128 + f0];
          float4 A0 = *(const float4*)(ap);
          float4 A1v = *(const float4*)(ap + 4);
          float4 A2 = *(const float4*)(ap + 8);
          float L[12] = {A0.x,A0.y,A0.z,A0.w,A1v.x,A1v.y,A1v.z,A1v.w,A2.x,A2.y,A2.z,A2.w};
          #pragma unroll
          for (int o = 0; o < 6; ++o){
            float4 wv = *(const float4*)&w3s[((oc0 + o)*8 + ci)*12 + kh*4];
            #pragma unroll
            for (int j = 0; j < 8; ++j)
              acc[o][j] = fmaf(L[j+2], wv.z, fmaf(L[j+1], wv.y, fmaf(L[j], wv.x, acc[o][j])));
          }
        }
      }
    }
  }
  __syncthreads();
  if (tid < 240){
    #pragma unroll
    for (int o = 0; o < 6; ++o){
      int oc = oc0 + o;
      float s = sc[oc], hs = sh[oc];
      #pragma unroll
      for (int jj = 0; jj < 4; ++jj){
        int fp = fg*4 + jj;
        if (fp < 57){
          float v0 = acc[o][2*jj] * s + hs;   v0 = v0 > 0.f ? v0 : 0.f;
          float v1 = acc[o][2*jj+1] * s + hs; v1 = v1 > 0.f ? v1 : 0.f;
          c3p[((b*96 + oc)*512 + t)*57 + fp] = v0 > v1 ? v0 : v1;
        }
      }
    }
  }
}

// ------- GEMM: acoustic = conv_feat @ fc_w.T + fc_b  (M=4096,K=5472,N=768) -------
__global__ __launch_bounds__(256) void gemm_fc_k(
    const float* __restrict__ c3p, const float* __restrict__ fcw,
    const float* __restrict__ fcb, float* __restrict__ ac)
{
  __shared__ float As[16*132];
  __shared__ float Bs[16*132];
  int tid = threadIdx.x;
  int m0 = blockIdx.x * 128, n0 = blockIdx.y * 128;
  int tm = (tid & 15) * 8, tn = (tid >> 4) * 8;
  float acc[8][8];
  #pragma unroll
  for (int i = 0; i < 8; ++i)
    #pragma unroll
    for (int j = 0; j < 8; ++j) acc[i][j] = 0.f;

  for (int k0 = 0; k0 < 5472; k0 += 16){
    __syncthreads();
    #pragma unroll
    for (int i = 0; i < 8; ++i){
      int idx = i*256 + tid;
      int k = idx & 15, mm = idx >> 4;
      int gk = k0 + k;
      int ci = (gk * 36793) >> 21;   // /57 magic, exact for gk<2^16
      int f  = gk - ci*57;
      int gm = m0 + mm;
      int bb = gm >> 9, tt = gm & 511;
      As[k*132 + mm] = c3p[((bb*96 + ci)*512 + tt)*57 + f];
      Bs[k*132 + mm] = fcw[(n0 + mm)*5472 + gk];
    }
    __syncthreads();
    #pragma unroll
    for (int k = 0; k < 16; ++k){
      const float* arow = &As[k*132 + tm];
      const float* brow = &Bs[k*132 + tn];
      float4 a0 = *(const float4*)arow, a1 = *(const float4*)(arow + 4);
      float4 b0 = *(const float4*)brow, b1 = *(const float4*)(brow + 4);
      float av[8] = {a0.x,a0.y,a0.z,a0.w,a1.x,a1.y,a1.z,a1.w};
      float bv[8] = {b0.x,b0.y,b0.z,b0.w,b1.x,b1.y,b1.z,b1.w};
      #pragma unroll
      for (int i = 0; i < 8; ++i)
        #pragma unroll
        for (int j = 0; j < 8; ++j)
          acc[i][j] = fmaf(av[i], bv[j], acc[i][j]);
    }
  }
  #pragma unroll
  for (int i = 0; i < 8; ++i){
    int gm = m0 + tm + i;
    #pragma unroll
    for (int j = 0; j < 8; ++j){
      int gn = n0 + tn + j;
      ac[gm*768 + gn] = acc[i][j] + fcb[gn];
    }
  }
}

// ------- GEMM: A1[t][row][b] = acoustic @ wih1[:, :768].T + bih1+bhh1 -------
__global__ __launch_bounds__(256) void gemm_a1_k(
    const float* __restrict__ ac, const float* __restrict__ wih1,
    const float* __restrict__ bih1, const float* __restrict__ bhh1,
    float* __restrict__ A1)
{
  __shared__ float As[16*132];
  __shared__ float Bs[16*132];
  int tid = threadIdx.x;
  int m0 = blockIdx.x * 128, n0 = blockIdx.y * 128;
  int tm = (tid & 15) * 8, tn = (tid >> 4) * 8;
  float acc[8][8];
  #pragma unroll
  for (int i = 0; i < 8; ++i)
    #pragma unroll
    for (int j = 0; j < 8; ++j) acc[i][j] = 0.f;

  for (int k0 = 0; k0 < 768; k0 += 16){
    __syncthreads();
    #pragma unroll
    for (int i = 0; i < 8; ++i){
      int idx = i*256 + tid;
      int k = idx & 15, mm = idx >> 4;
      int gk = k0 + k;
      As[k*132 + mm] = ac[(m0 + mm)*768 + gk];
      Bs[k*132 + mm] = wih1[(n0 + mm)*944 + gk];
    }
    __syncthreads();
    #pragma unroll
    for (int k = 0; k < 16; ++k){
      const float* arow = &As[k*132 + tm];
      const float* brow = &Bs[k*132 + tn];
      float4 a0 = *(const float4*)arow, a1 = *(const float4*)(arow + 4);
      float4 b0 = *(const float4*)brow, b1 = *(const float4*)(brow + 4);
      float av[8] = {a0.x,a0.y,a0.z,a0.w,a1.x,a1.y,a1.z,a1.w};
      float bv[8] = {b0.x,b0.y,b0.z,b0.w,b1.x,b1.y,b1.z,b1.w};
      #pragma unroll
      for (int i = 0; i < 8; ++i)
        #pragma unroll
        for (int j = 0; j < 8; ++j)
          acc[i][j] = fmaf(av[i], bv[j], acc[i][j]);
    }
  }
  #pragma unroll
  for (int i = 0; i < 8; ++i){
    int gm = m0 + tm + i;
    int tt = gm & 511, bb = gm >> 9;
    #pragma unroll
    for (int j = 0; j < 8; ++j){
      int gn = n0 + tn + j;
      A1[tt*24576 + gn*8 + bb] = acc[i][j] + bih1[gn] + bhh1[gn];
    }
  }
}

// ---------------- persistent recurrent kernel ----------------
// 256 WGs x 256 threads, plain launch. Co-residency: 1 WG/CU guaranteed
// (4 waves, 43.5KB LDS). All cross-WG state (xbuf, h2b, sy) accessed with
// system-scope relaxed atomics (sc0sc1 cache-bypass) -> no threadfence,
// no L2 flush, weights/A1 stay cached.
__global__ __launch_bounds__(256, 1) void rec_k(
    const float* __restrict__ A1,
    const float* __restrict__ whh1, const float* __restrict__ wih1,
    const float* __restrict__ wih2, const float* __restrict__ whh2,
    const float* __restrict__ bih2, const float* __restrict__ bhh2,
    const float* __restrict__ postw, const float* __restrict__ postb,
    const float* __restrict__ embw,
    float* __restrict__ xbuf, float* __restrict__ h2b,
    unsigned* __restrict__ sy, float* __restrict__ out)
{
  const int wg = blockIdx.x, tid = threadIdx.x;
  const int wv = tid >> 6, l = tid & 63;
  __shared__ float red[40*268];   // stages A/B use as [96][68]
  __shared__ float zbuf[96];

  float wA[15][3];
  float wB[24][3];
  float wC[3][5];
  {
    int Rb = wv*768 + wg*3;
    #pragma unroll
    for (int ki = 0; ki < 15; ++ki){
      int k = l + (ki << 6);
      #pragma unroll
      for (int u = 0; u < 3; ++u){
        float w = 0.f;
        if (k < 768) w = whh1[(Rb + u)*768 + k];
        else if (k < 944) w = wih1[(Rb + u)*944 + k];
        wA[ki][u] = w;
      }
    }
    #pragma unroll
    for (int ki = 0; ki < 24; ++ki){
      int k = l + (ki << 6);
      #pragma unroll
      for (int u = 0; u < 3; ++u)
        wB[ki][u] = (k < 768) ? wih2[(Rb + u)*768 + k] : whh2[(Rb + u)*768 + k - 768];
    }
  }
  if (wg < 88){
    #pragma unroll
    for (int kc = 0; kc < 3; ++kc)
      #pragma unroll
      for (int s = 0; s < 5; ++s)
        wC[kc][s] = postw[(wg*5 + s)*768 + tid + (kc << 8)];
  }
  float b2r = 0.f; int fR = 0, fb = 0;
  if (tid < 96){
    int g = tid / 24, rem = tid - g*24;
    int u = rem >> 3; fb = rem & 7;
    fR = g*768 + wg*3 + u;
    b2r = bih2[fR] + bhh2[fR];
  }
  float pbr = (wg < 88 && tid < 40) ? postb[wg*5 + (tid >> 3)] : 0.f;
  float c1r = 0.f, c2r = 0.f;

  if (wg == 0){
    for (int idx = tid; idx < 1408; idx += 256){
      int e = idx >> 3, bb = idx & 7;
      cstore(&xbuf[(768 + e)*8 + bb], embw[e & 1]);   // emb(prev=0) for step 0
    }
  }
  unsigned bar = 1;
  gbar(sy, bar);

  for (int t = 0; t < 512; ++t){
    const int cur = t & 1, nxt = cur ^ 1;
    float* xc  = xbuf + cur * 7552;
    float* xn  = xbuf + nxt * 7552;
    float* h2c = h2b + cur * 6144;
    float* h2n = h2b + nxt * 6144;

    // ---- stage A: gates1 = A1[t] + [h1,emb] @ [whh1|We].T ; cell1 ----
    {
      float acc[3][8];
      #pragma unroll
      for (int u = 0; u < 3; ++u)
        #pragma unroll
        for (int j = 0; j < 8; ++j) acc[u][j] = 0.f;
      #pragma unroll
      for (int ki = 0; ki < 15; ++ki){
        int k = l + (ki << 6);
        if (k < 944){
          const float* xp = xc + k*8;
          float x0 = cload(xp+0), x1 = cload(xp+1), x2 = cload(xp+2), x3 = cload(xp+3);
          float x4 = cload(xp+4), x5 = cload(xp+5), x6 = cload(xp+6), x7 = cload(xp+7);
          #pragma unroll
          for (int u = 0; u < 3; ++u){
            float w = wA[ki][u];
            acc[u][0] = fmaf(w, x0, acc[u][0]);
            acc[u][1] = fmaf(w, x1, acc[u][1]);
            acc[u][2] = fmaf(w, x2, acc[u][2]);
            acc[u][3] = fmaf(w, x3, acc[u][3]);
            acc[u][4] = fmaf(w, x4, acc[u][4]);
            acc[u][5] = fmaf(w, x5, acc[u][5]);
            acc[u][6] = fmaf(w, x6, acc[u][6]);
            acc[u][7] = fmaf(w, x7, acc[u][7]);
          }
        }
      }
      #pragma unroll
      for (int u = 0; u < 3; ++u)
        #pragma unroll
        for (int j = 0; j < 8; ++j)
          red[(wv*24 + u*8 + j)*68 + l] = acc[u][j];
      __syncthreads();
      if (tid < 96){
        const float4* rp = (const float4*)(red + tid*68);
        float sum = 0.f;
        #pragma unroll
        for (int q = 0; q < 16; ++q){
          float4 r4 = rp[q];
          sum += (r4.x + r4.y) + (r4.z + r4.w);
        }
        sum += A1[t*24576 + fR*8 + fb];
        zbuf[tid] = sum;
      }
      __syncthreads();
      if (tid < 24){
        float zi = zbuf[tid], zf = zbuf[24 + tid], zg = zbuf[48 + tid], zo = zbuf[72 + tid];
        c1r = sigm(zf)*c1r + sigm(zi)*tanhf(zg);
        float hh = sigm(zo)*tanhf(c1r);
        cstore(&xn[(wg*3 + (tid >> 3))*8 + (tid & 7)], hh);
      }
      ++bar; gbar(sy, bar);
    }

    // ---- stage B: gates2 = h1n @ wih2.T + h2 @ whh2.T + b ; cell2 ----
    {
      float acc[3][8];
      #pragma unroll
      for (int u = 0; u < 3; ++u)
        #pragma unroll
        for (int j = 0; j < 8; ++j) acc[u][j] = 0.f;
      #pragma unroll
      for (int ki = 0; ki < 24; ++ki){
        int k = l + (ki << 6);
        const float* src = (ki < 12) ? (xn + k*8) : (h2c + (k - 768)*8);
        float x0 = cload(src+0), x1 = cload(src+1), x2 = cload(src+2), x3 = cload(src+3);
        float x4 = cload(src+4), x5 = cload(src+5), x6 = cload(src+6), x7 = cload(src+7);
        #pragma unroll
        for (int u = 0; u < 3; ++u){
          float w = wB[ki][u];
          acc[u][0] = fmaf(w, x0, acc[u][0]);
          acc[u][1] = fmaf(w, x1, acc[u][1]);
          acc[u][2] = fmaf(w, x2, acc[u][2]);
          acc[u][3] = fmaf(w, x3, acc[u][3]);
          acc[u][4] = fmaf(w, x4, acc[u][4]);
          acc[u][5] = fmaf(w, x5, acc[u][5]);
          acc[u][6] = fmaf(w, x6, acc[u][6]);
          acc[u][7] = fmaf(w, x7, acc[u][7]);
        }
      }
      #pragma unroll
      for (int u = 0; u < 3; ++u)
        #pragma unroll
        for (int j = 0; j < 8; ++j)
          red[(wv*24 + u*8 + j)*68 + l] = acc[u][j];
      __syncthreads();
      if (tid < 96){
        const float4* rp = (const float4*)(red + tid*68);
        float sum = 0.f;
        #pragma unroll
        for (int q = 0; q < 16; ++q){
          float4 r4 = rp[q];
          sum += (r4.x + r4.y) + (r4.z + r4.w);
        }
        sum += b2r;
        zbuf[tid] = sum;
      }
      __syncthreads();
      if (tid < 24){
        float zi = zbuf[tid], zf = zbuf[24 + tid], zg = zbuf[48 + tid], zo = zbuf[72 + tid];
        c2r = sigm(zf)*c2r + sigm(zi)*tanhf(zg);
        float hh = sigm(zo)*tanhf(c2r);
        cstore(&h2n[(wg*3 + (tid >> 3))*8 + (tid & 7)], hh);
      }
      ++bar; gbar(sy, bar);
    }

    // ---- stage C: logits for pitch wg; argmax -> emb for next step ----
    if (wg < 88){
      float acc[5][8];
      #pragma unroll
      for (int s = 0; s < 5; ++s)
        #pragma unroll
        for (int j = 0; j < 8; ++j) acc[s][j] = 0.f;
      #pragma unroll
      for (int kc = 0; kc < 3; ++kc){
        int k = tid + (kc << 8);
        const float* xp = h2n + k*8;
        float x0 = cload(xp+0), x1 = cload(xp+1), x2 = cload(xp+2), x3 = cload(xp+3);
        float x4 = cload(xp+4), x5 = cload(xp+5), x6 = cload(xp+6), x7 = cload(xp+7);
        #pragma unroll
        for (int s = 0; s < 5; ++s){
          float w = wC[kc][s];
          acc[s][0] = fmaf(w, x0, acc[s][0]);
          acc[s][1] = fmaf(w, x1, acc[s][1]);
          acc[s][2] = fmaf(w, x2, acc[s][2]);
          acc[s][3] = fmaf(w, x3, acc[s][3]);
          acc[s][4] = fmaf(w, x4, acc[s][4]);
          acc[s][5] = fmaf(w, x5, acc[s][5]);
          acc[s][6] = fmaf(w, x6, acc[s][6]);
          acc[s][7] = fmaf(w, x7, acc[s][7]);
        }
      }
      #pragma unroll
      for (int s = 0; s < 5; ++s)
        #pragma unroll
        for (int j = 0; j < 8; ++j)
          red[(s*8 + j)*268 + tid] = acc[s][j];
      __syncthreads();
      if (tid < 40){
        const float4* rp = (const float4*)(red + tid*268);
        float sum = 0.f;
        #pragma unroll
        for (int q = 0; q < 64; ++q){
          float4 r4 = rp[q];
          sum += (r4.x + r4.y) + (r4.z + r4.w);
        }
        sum += pbr;
        int s = tid >> 3, bb = tid & 7;
        out[bb*225280 + t*440 + wg*5 + s] = sum;
        zbuf[tid] = sum;
      }
      __syncthreads();
      if (tid < 8){
        float best = zbuf[tid]; int bs = 0;
        #pragma unroll
        for (int s = 1; s < 5; ++s){
          float v = zbuf[s*8 + tid];
          if (v > best){ best = v; bs = s; }   // first max wins (jnp.argmax)
        }
        cstore(&xn[(768 + wg*2)*8 + tid],     embw[bs*2]);
        cstore(&xn[(768 + wg*2 + 1)*8 + tid], embw[bs*2 + 1]);
      }
    }
    ++bar; gbar(sy, bar);
  }
}

extern "C" void kernel_launch(void* const* d_in, const int* in_sizes, int n_in,
                              void* d_out, int out_size, void* d_ws, size_t ws_size,
                              hipStream_t stream)
{
  (void)in_sizes; (void)n_in; (void)out_size; (void)ws_size;
  const float* mel  = (const float*)d_in[0];
  const float* w1   = (const float*)d_in[1];
  const float* b1   = (const float*)d_in[2];
  const float* g1   = (const float*)d_in[3];
  const float* be1  = (const float*)d_in[4];
  const float* m1   = (const float*)d_in[5];
  const float* v1   = (const float*)d_in[6];
  const float* w2   = (const float*)d_in[7];
  const float* b2   = (const float*)d_in[8];
  const float* g2   = (const float*)d_in[9];
  const float* be2  = (const float*)d_in[10];
  const float* m2   = (const float*)d_in[11];
  const float* v2   = (const float*)d_in[12];
  const float* w3   = (const float*)d_in[13];
  const float* b3   = (const float*)d_in[14];
  const float* g3   = (const float*)d_in[15];
  const float* be3  = (const float*)d_in[16];
  const float* m3   = (const float*)d_in[17];
  const float* v3   = (const float*)d_in[18];
  const float* fcw  = (const float*)d_in[19];
  const float* fcb  = (const float*)d_in[20];
  const float* wih1 = (const float*)d_in[21];
  const float* whh1 = (const float*)d_in[22];
  const float* bih1 = (const float*)d_in[23];
  const float* bhh1 = (const float*)d_in[24];
  const float* wih2 = (const float*)d_in[25];
  const float* whh2 = (const float*)d_in[26];
  const float* bih2 = (const float*)d_in[27];
  const float* bhh2 = (const float*)d_in[28];
  const float* postw= (const float*)d_in[29];
  const float* postb= (const float*)d_in[30];
  const float* embw = (const float*)d_in[31];

  float* ws    = (float*)d_ws;
  float* c3p   = ws + WS_C3;
  float* c2ch  = ws + WS_C2CH;
  float* ac    = ws + WS_AC;
  float* A1    = ws + WS_A1;
  float* st    = ws + WS_ST;
  float* xbuf  = st;
  float* h2b   = st + 15104;
  unsigned* sy = (unsigned*)(st + 27392);
  float* outp  = (float*)d_out;

  // zero recurrent state + barrier counters (ws is re-poisoned before each launch)
  hipMemsetAsync(st, 0, 27648 * sizeof(float), stream);

  // conv stack, time-chunked (4 chunks of 128), chunk dependency via stream order
  for (int c = 0; c < 4; ++c){
    int t0 = c * 128;
    conv2f_k<<<dim3(8*130), dim3(256), 0, stream>>>(
        mel, w1, b1, g1, be1, m1, v1, w2, b2, g2, be2, m2, v2, c2ch, t0);
    conv3_k<<<dim3(8*128), dim3(256), 0, stream>>>(
        c2ch, w3, b3, g3, be3, m3, v3, c3p, t0);
  }
  gemm_fc_k<<<dim3(32, 6), dim3(256), 0, stream>>>(c3p, fcw, fcb, ac);
  gemm_a1_k<<<dim3(32, 24), dim3(256), 0, stream>>>(ac, wih1, bih1, bhh1, A1);

  // plain launch: 256 WGs co-resident by construction (1 WG/CU resources)
  rec_k<<<dim3(256), dim3(256), 0, stream>>>(
      A1, whh1, wih1, wih2, whh2, bih2, bhh2, postw, postb, embw,
      xbuf, h2b, sy, outp);
}

// Round 5
// 25603.400 us; speedup vs baseline: 1.2335x; 1.1348x over previous
//
#include <hip/hip_runtime.h>
#include <math.h>

// ---------------- ws layout (float offsets), total ~119.3 MiB ----------------
#define WS_C3   0u
#define WS_C2CH 22413312u
#define WS_AC   28104192u
#define WS_A1   0u
#define WS_ST   31249920u

__device__ __forceinline__ float sigm(float x){ return 1.0f / (1.0f + expf(-x)); }

// Fine-grained coherent access (sc0 sc1): bypasses L1/L2, served at the
// Infinity-Cache coherence point — cross-XCD visible without cache flushes.
__device__ __forceinline__ float cload(const float* p){
  unsigned u = __hip_atomic_load((const unsigned*)p, __ATOMIC_RELAXED,
                                 __HIP_MEMORY_SCOPE_SYSTEM);
  union { unsigned u; float f; } c; c.u = u; return c.f;
}
__device__ __forceinline__ void cstore(float* p, float v){
  union { float f; unsigned u; } c; c.f = v;
  __hip_atomic_store((unsigned*)p, c.u, __ATOMIC_RELAXED,
                     __HIP_MEMORY_SCOPE_SYSTEM);
}
__device__ __forceinline__ void cload64(const float* p, float& a, float& b){
  unsigned long long u = __hip_atomic_load((const unsigned long long*)p,
                          __ATOMIC_RELAXED, __HIP_MEMORY_SCOPE_SYSTEM);
  union { unsigned long long u; float f[2]; } c; c.u = u;
  a = c.f[0]; b = c.f[1];
}

// two-level grid barrier (unchanged from round 4 — proven correct).
__device__ __forceinline__ void gbar(unsigned* sy, unsigned bar){
  __syncthreads();   // drains vmcnt(0): all lanes' coherent stores visible
  if (threadIdx.x == 0){
    unsigned g = blockIdx.x >> 5;
    unsigned v = __hip_atomic_fetch_add(&sy[16 + (g << 4)], 1u,
                                        __ATOMIC_RELAXED, __HIP_MEMORY_SCOPE_SYSTEM);
    if (v == bar*32u - 1u)
      __hip_atomic_fetch_add(&sy[0], 1u,
                             __ATOMIC_RELAXED, __HIP_MEMORY_SCOPE_SYSTEM);
    while (__hip_atomic_load(&sy[0], __ATOMIC_RELAXED, __HIP_MEMORY_SCOPE_SYSTEM) < bar*8u)
      __builtin_amdgcn_s_sleep(2);
  }
  __syncthreads();
}

// ------- conv2f: fused conv1+bn1+relu -> conv2+bn2+relu+pool(1,2) -------
__global__ __launch_bounds__(256) void conv2f_k(
    const float* __restrict__ mel, const float* __restrict__ w1,
    const float* __restrict__ b1, const float* __restrict__ g1,
    const float* __restrict__ be1, const float* __restrict__ m1,
    const float* __restrict__ v1,
    const float* __restrict__ w2, const float* __restrict__ b2,
    const float* __restrict__ g2, const float* __restrict__ be2,
    const float* __restrict__ m2, const float* __restrict__ v2,
    float* __restrict__ c2ch, int t0)
{
  __shared__ float act[3*8*240];
  __shared__ float w2s[48*8*12];
  __shared__ float mel5[5*240];
  __shared__ float w1s[48*12];
  __shared__ float sc1[48], sh1[48], sc2[48], sh2[48];
  int tid = threadIdx.x;
  int b = blockIdx.x / 130, lt = blockIdx.x - b*130;
  int t = t0 - 1 + lt;

  int fg = tid % 29, ocg = tid / 29;
  int f0 = fg * 8, oc0 = ocg * 6;

  if (t < 0 || t > 511){
    if (tid < 232){
      for (int o = 0; o < 6; ++o)
        for (int jj = 0; jj < 4; ++jj){
          int fp = fg*4 + jj;
          if (fp < 114)
            c2ch[((b*48 + oc0 + o)*130 + lt)*114 + fp] = 0.f;
        }
    }
    return;
  }

  for (int idx = tid; idx < 5*240; idx += 256){
    int rr = idx / 240, w = idx - rr*240;
    int tt = t + rr - 2, f = w - 2;
    mel5[idx] = (tt >= 0 && tt < 512 && f >= 0 && f < 229)
                ? mel[(b*512 + tt)*229 + f] : 0.f;
  }
  for (int idx = tid; idx < 48*12; idx += 256){
    int c = idx / 12, q = idx - c*12;
    int kh = q >> 2, kw = q & 3;
    w1s[idx] = (kw < 3) ? w1[c*9 + kh*3 + kw] : 0.f;
  }
  if (tid < 48){
    float s1 = g1[tid] / sqrtf(v1[tid] + 1e-5f);
    sc1[tid] = s1; sh1[tid] = be1[tid] + (b1[tid] - m1[tid]) * s1;
    float s2 = g2[tid] / sqrtf(v2[tid] + 1e-5f);
    sc2[tid] = s2; sh2[tid] = be2[tid] + (b2[tid] - m2[tid]) * s2;
  }

  float acc[6][8];
  #pragma unroll
  for (int o = 0; o < 6; ++o)
    #pragma unroll
    for (int j = 0; j < 8; ++j) acc[o][j] = 0.f;

  for (int ch = 0; ch < 6; ++ch){
    int ci0 = ch * 8;
    __syncthreads();
    for (int idx = tid; idx < 3*8*240; idx += 256){
      int rr = idx / 1920;
      int rem = idx - rr*1920;
      int ci = rem / 240, w = rem - ci*240;
      int tt = t + rr - 1, f = w - 1;
      float val = 0.f;
      if (tt >= 0 && tt < 512 && f >= 0 && f < 229){
        int cg = ci0 + ci;
        float a = 0.f;
        #pragma unroll
        for (int dh = 0; dh < 3; ++dh){
          const float* mr = &mel5[(rr + dh)*240 + w];
          a = fmaf(mr[0], w1s[cg*12 + dh*4 + 0], a);
          a = fmaf(mr[1], w1s[cg*12 + dh*4 + 1], a);
          a = fmaf(mr[2], w1s[cg*12 + dh*4 + 2], a);
        }
        a = a * sc1[cg] + sh1[cg];
        val = a > 0.f ? a : 0.f;
      }
      act[idx] = val;
    }
    for (int idx = tid; idx < 48*8*12; idx += 256){
      int oc = idx / 96;
      int rem = idx - oc*96;
      int ci = rem / 12, q = rem - ci*12;
      int kh = q >> 2, kw = q & 3;
      w2s[idx] = (kw < 3) ? w2[(oc*48 + ci0 + ci)*9 + kh*3 + kw] : 0.f;
    }
    __syncthreads();
    if (tid < 232){
      for (int ci = 0; ci < 8; ++ci){
        #pragma unroll
        for (int kh = 0; kh < 3; ++kh){
          const float* ap = &act[(kh*8 + ci)*240 + f0];
          float4 A0 = *(const float4*)(ap);
          float4 A1v = *(const float4*)(ap + 4);
          float4 A2 = *(const float4*)(ap + 8);
          float L[12] = {A0.x,A0.y,A0.z,A0.w,A1v.x,A1v.y,A1v.z,A1v.w,A2.x,A2.y,A2.z,A2.w};
          #pragma unroll
          for (int o = 0; o < 6; ++o){
            float4 wv = *(const float4*)&w2s[((oc0 + o)*8 + ci)*12 + kh*4];
            #pragma unroll
            for (int j = 0; j < 8; ++j)
              acc[o][j] = fmaf(L[j+2], wv.z, fmaf(L[j+1], wv.y, fmaf(L[j], wv.x, acc[o][j])));
          }
        }
      }
    }
  }
  __syncthreads();
  if (tid < 232){
    #pragma unroll
    for (int o = 0; o < 6; ++o){
      int oc = oc0 + o;
      float s = sc2[oc], hs = sh2[oc];
      #pragma unroll
      for (int jj = 0; jj < 4; ++jj){
        int fp = fg*4 + jj;
        if (fp < 114){
          float v0 = acc[o][2*jj] * s + hs;   v0 = v0 > 0.f ? v0 : 0.f;
          float v1 = acc[o][2*jj+1] * s + hs; v1 = v1 > 0.f ? v1 : 0.f;
          c2ch[((b*48 + oc)*130 + lt)*114 + fp] = v0 > v1 ? v0 : v1;
        }
      }
    }
  }
}

// ------- conv3 (48->96) + bn + relu + pool(1,2) -------
__global__ __launch_bounds__(256) void conv3_k(
    const float* __restrict__ c2ch, const float* __restrict__ w3,
    const float* __restrict__ b3, const float* __restrict__ g3,
    const float* __restrict__ be3, const float* __restrict__ m3,
    const float* __restrict__ v3, float* __restrict__ c3p, int t0)
{
  __shared__ float act[3*8*128];
  __shared__ float w3s[96*8*12];
  __shared__ float sc[96], sh[96];
  int tid = threadIdx.x;
  int b = blockIdx.x >> 7, tl = blockIdx.x & 127;
  int t = t0 + tl;
  if (tid < 96){
    float s = g3[tid] / sqrtf(v3[tid] + 1e-5f);
    sc[tid] = s; sh[tid] = be3[tid] + (b3[tid] - m3[tid]) * s;
  }
  int fg = tid % 15, ocg = tid / 15;
  int f0 = fg * 8, oc0 = ocg * 6;
  float acc[6][8];
  #pragma unroll
  for (int o = 0; o < 6; ++o)
    #pragma unroll
    for (int j = 0; j < 8; ++j) acc[o][j] = 0.f;

  for (int ch = 0; ch < 6; ++ch){
    int ci0 = ch * 8;
    __syncthreads();
    for (int idx = tid; idx < 3*8*128; idx += 256){
      int rr = idx >> 10;
      int rem = idx & 1023;
      int ci = rem >> 7, w = rem & 127;
      int lt = tl + rr;
      int f = w - 1;
      float val = 0.f;
      if (f >= 0 && f < 114)
        val = c2ch[((b*48 + ci0 + ci)*130 + lt)*114 + f];
      act[idx] = val;
    }
    for (int idx = tid; idx < 96*8*12; idx += 256){
      int oc = idx / 96;
      int rem = idx - oc*96;
      int ci = rem / 12, q = rem - ci*12;
      int kh = q >> 2, kw = q & 3;
      w3s[idx] = (kw < 3) ? w3[(oc*48 + ci0 + ci)*9 + kh*3 + kw] : 0.f;
    }
    __syncthreads();
    if (tid < 240){
      for (int ci = 0; ci < 8; ++ci){
        #pragma unroll
        for (int kh = 0; kh < 3; ++kh){
          const float* ap = &act[(kh*8 + ci)*128 + f0];
          float4 A0 = *(const float4*)(ap);
          float4 A1v = *(const float4*)(ap + 4);
          float4 A2 = *(const float4*)(ap + 8);
          float L[12] = {A0.x,A0.y,A0.z,A0.w,A1v.x,A1v.y,A1v.z,A1v.w,A2.x,A2.y,A2.z,A2.w};
          #pragma unroll
          for (int o = 0; o < 6; ++o){
            float4 wv = *(const float4*)&w3s[((oc0 + o)*8 + ci)*12 + kh*4];
            #pragma unroll
            for (int j = 0; j < 8; ++j)
              acc[o][j] = fmaf(L[j+2], wv.z, fmaf(L[j+1], wv.y, fmaf(L[j], wv.x, acc[o][j])));
          }
        }
      }
    }
  }
  __syncthreads();
  if (tid < 240){
    #pragma unroll
    for (int o = 0; o < 6; ++o){
      int oc = oc0 + o;
      float s = sc[oc], hs = sh[oc];
      #pragma unroll
      for (int jj = 0; jj < 4; ++jj){
        int fp = fg*4 + jj;
        if (fp < 57){
          float v0 = acc[o][2*jj] * s + hs;   v0 = v0 > 0.f ? v0 : 0.f;
          float v1 = acc[o][2*jj+1] * s + hs; v1 = v1 > 0.f ? v1 : 0.f;
          c3p[((b*96 + oc)*512 + t)*57 + fp] = v0 > v1 ? v0 : v1;
        }
      }
    }
  }
}

// ------- GEMM: acoustic = conv_feat @ fc_w.T + fc_b -------
__global__ __launch_bounds__(256) void gemm_fc_k(
    const float* __restrict__ c3p, const float* __restrict__ fcw,
    const float* __restrict__ fcb, float* __restrict__ ac)
{
  __shared__ float As[16*132];
  __shared__ float Bs[16*132];
  int tid = threadIdx.x;
  int m0 = blockIdx.x * 128, n0 = blockIdx.y * 128;
  int tm = (tid & 15) * 8, tn = (tid >> 4) * 8;
  float acc[8][8];
  #pragma unroll
  for (int i = 0; i < 8; ++i)
    #pragma unroll
    for (int j = 0; j < 8; ++j) acc[i][j] = 0.f;

  for (int k0 = 0; k0 < 5472; k0 += 16){
    __syncthreads();
    #pragma unroll
    for (int i = 0; i < 8; ++i){
      int idx = i*256 + tid;
      int k = idx & 15, mm = idx >> 4;
      int gk = k0 + k;
      int ci = (gk * 36793) >> 21;
      int f  = gk - ci*57;
      int gm = m0 + mm;
      int bb = gm >> 9, tt = gm & 511;
      As[k*132 + mm] = c3p[((bb*96 + ci)*512 + tt)*57 + f];
      Bs[k*132 + mm] = fcw[(n0 + mm)*5472 + gk];
    }
    __syncthreads();
    #pragma unroll
    for (int k = 0; k < 16; ++k){
      const float* arow = &As[k*132 + tm];
      const float* brow = &Bs[k*132 + tn];
      float4 a0 = *(const float4*)arow, a1 = *(const float4*)(arow + 4);
      float4 b0 = *(const float4*)brow, b1 = *(const float4*)(brow + 4);
      float av[8] = {a0.x,a0.y,a0.z,a0.w,a1.x,a1.y,a1.z,a1.w};
      float bv[8] = {b0.x,b0.y,b0.z,b0.w,b1.x,b1.y,b1.z,b1.w};
      #pragma unroll
      for (int i = 0; i < 8; ++i)
        #pragma unroll
        for (int j = 0; j < 8; ++j)
          acc[i][j] = fmaf(av[i], bv[j], acc[i][j]);
    }
  }
  #pragma unroll
  for (int i = 0; i < 8; ++i){
    int gm = m0 + tm + i;
    #pragma unroll
    for (int j = 0; j < 8; ++j){
      int gn = n0 + tn + j;
      ac[gm*768 + gn] = acc[i][j] + fcb[gn];
    }
  }
}

// ------- GEMM: A1[t][row][b] = acoustic @ wih1[:, :768].T + bih1+bhh1 -------
__global__ __launch_bounds__(256) void gemm_a1_k(
    const float* __restrict__ ac, const float* __restrict__ wih1,
    const float* __restrict__ bih1, const float* __restrict__ bhh1,
    float* __restrict__ A1)
{
  __shared__ float As[16*132];
  __shared__ float Bs[16*132];
  int tid = threadIdx.x;
  int m0 = blockIdx.x * 128, n0 = blockIdx.y * 128;
  int tm = (tid & 15) * 8, tn = (tid >> 4) * 8;
  float acc[8][8];
  #pragma unroll
  for (int i = 0; i < 8; ++i)
    #pragma unroll
    for (int j = 0; j < 8; ++j) acc[i][j] = 0.f;

  for (int k0 = 0; k0 < 768; k0 += 16){
    __syncthreads();
    #pragma unroll
    for (int i = 0; i < 8; ++i){
      int idx = i*256 + tid;
      int k = idx & 15, mm = idx >> 4;
      int gk = k0 + k;
      As[k*132 + mm] = ac[(m0 + mm)*768 + gk];
      Bs[k*132 + mm] = wih1[(n0 + mm)*944 + gk];
    }
    __syncthreads();
    #pragma unroll
    for (int k = 0; k < 16; ++k){
      const float* arow = &As[k*132 + tm];
      const float* brow = &Bs[k*132 + tn];
      float4 a0 = *(const float4*)arow, a1 = *(const float4*)(arow + 4);
      float4 b0 = *(const float4*)brow, b1 = *(const float4*)(brow + 4);
      float av[8] = {a0.x,a0.y,a0.z,a0.w,a1.x,a1.y,a1.z,a1.w};
      float bv[8] = {b0.x,b0.y,b0.z,b0.w,b1.x,b1.y,b1.z,b1.w};
      #pragma unroll
      for (int i = 0; i < 8; ++i)
        #pragma unroll
        for (int j = 0; j < 8; ++j)
          acc[i][j] = fmaf(av[i], bv[j], acc[i][j]);
    }
  }
  #pragma unroll
  for (int i = 0; i < 8; ++i){
    int gm = m0 + tm + i;
    int tt = gm & 511, bb = gm >> 9;
    #pragma unroll
    for (int j = 0; j < 8; ++j){
      int gn = n0 + tn + j;
      A1[tt*24576 + gn*8 + bb] = acc[i][j] + bih1[gn] + bhh1[gn];
    }
  }
}

// ---------------- persistent recurrent kernel ----------------
// Per stage: barrier -> sector-perfect coherent copy of the shared vector
// into LDS (b-major, odd plane stride => conflict-free ds_read) -> registers
// compute -> wave shuffle-reduce -> tiny coherent writeback.
#define SA 945
#define SB 1537
#define SC 769
__global__ __launch_bounds__(256, 1) void rec_k(
    const float* __restrict__ A1,
    const float* __restrict__ whh1, const float* __restrict__ wih1,
    const float* __restrict__ wih2, const float* __restrict__ whh2,
    const float* __restrict__ bih2, const float* __restrict__ bhh2,
    const float* __restrict__ postw, const float* __restrict__ postb,
    const float* __restrict__ embw,
    float* __restrict__ xbuf, float* __restrict__ h2b,
    unsigned* __restrict__ sy, float* __restrict__ out)
{
  const int wg = blockIdx.x, tid = threadIdx.x;
  const int wv = tid >> 6, l = tid & 63;
  __shared__ float xs[8*SB];     // 49.2 KB staging (max: stage B)
  __shared__ float zbuf[96];
  __shared__ float red2[40*4];

  float wA[15][3];
  float wB[24][3];
  float wC[3][5];
  {
    int Rb = wv*768 + wg*3;
    #pragma unroll
    for (int ki = 0; ki < 15; ++ki){
      int k = l + (ki << 6);
      #pragma unroll
      for (int u = 0; u < 3; ++u){
        float w = 0.f;
        if (k < 768) w = whh1[(Rb + u)*768 + k];
        else if (k < 944) w = wih1[(Rb + u)*944 + k];
        wA[ki][u] = w;
      }
    }
    #pragma unroll
    for (int ki = 0; ki < 24; ++ki){
      int k = l + (ki << 6);
      #pragma unroll
      for (int u = 0; u < 3; ++u)
        wB[ki][u] = (k < 768) ? wih2[(Rb + u)*768 + k] : whh2[(Rb + u)*768 + k - 768];
    }
  }
  if (wg < 88){
    #pragma unroll
    for (int kc = 0; kc < 3; ++kc)
      #pragma unroll
      for (int s = 0; s < 5; ++s)
        wC[kc][s] = postw[(wg*5 + s)*768 + tid + (kc << 8)];
  }
  float b2r = 0.f; int fR = 0, fb = 0;
  if (tid < 96){
    int g = tid / 24, rem = tid - g*24;
    int u = rem >> 3; fb = rem & 7;
    fR = g*768 + wg*3 + u;
    b2r = bih2[fR] + bhh2[fR];
  }
  float pbr = (wg < 88 && tid < 40) ? postb[wg*5 + (tid >> 3)] : 0.f;
  float c1r = 0.f, c2r = 0.f;

  if (wg == 0){
    for (int idx = tid; idx < 1408; idx += 256){
      int e = idx >> 3, bb = idx & 7;
      cstore(&xbuf[(768 + e)*8 + bb], embw[e & 1]);   // emb(prev=0) for step 0
    }
  }
  unsigned bar = 1;
  gbar(sy, bar);

  for (int t = 0; t < 512; ++t){
    const int cur = t & 1, nxt = cur ^ 1;
    float* xc  = xbuf + cur * 7552;
    float* xn  = xbuf + nxt * 7552;
    float* h2c = h2b + cur * 6144;
    float* h2n = h2b + nxt * 6144;

    // ---- stage A: gates1 = A1[t] + [h1,emb] @ [whh1|We].T ; cell1 ----
    {
      for (int idx = tid; idx < 3776; idx += 256){   // 944*8/2 u64 words
        float a, b; cload64(xc + 2*idx, a, b);
        int k = idx >> 2, p = (idx & 3) << 1;
        xs[p*SA + k]       = a;
        xs[(p + 1)*SA + k] = b;
      }
      __syncthreads();
      float acc[3][8];
      #pragma unroll
      for (int u = 0; u < 3; ++u)
        #pragma unroll
        for (int j = 0; j < 8; ++j) acc[u][j] = 0.f;
      #pragma unroll
      for (int ki = 0; ki < 15; ++ki){
        int k = l + (ki << 6);
        if (k < 944){
          float x0 = xs[k],        x1 = xs[SA + k],   x2 = xs[2*SA + k], x3 = xs[3*SA + k];
          float x4 = xs[4*SA + k], x5 = xs[5*SA + k], x6 = xs[6*SA + k], x7 = xs[7*SA + k];
          #pragma unroll
          for (int u = 0; u < 3; ++u){
            float w = wA[ki][u];
            acc[u][0] = fmaf(w, x0, acc[u][0]);
            acc[u][1] = fmaf(w, x1, acc[u][1]);
            acc[u][2] = fmaf(w, x2, acc[u][2]);
            acc[u][3] = fmaf(w, x3, acc[u][3]);
            acc[u][4] = fmaf(w, x4, acc[u][4]);
            acc[u][5] = fmaf(w, x5, acc[u][5]);
            acc[u][6] = fmaf(w, x6, acc[u][6]);
            acc[u][7] = fmaf(w, x7, acc[u][7]);
          }
        }
      }
      #pragma unroll
      for (int u = 0; u < 3; ++u)
        #pragma unroll
        for (int j = 0; j < 8; ++j){
          float s = acc[u][j];
          s += __shfl_xor(s, 1);  s += __shfl_xor(s, 2);  s += __shfl_xor(s, 4);
          s += __shfl_xor(s, 8);  s += __shfl_xor(s, 16); s += __shfl_xor(s, 32);
          if (l == 0) zbuf[wv*24 + u*8 + j] = s;
        }
      __syncthreads();
      if (tid < 96)
        zbuf[tid] += A1[t*24576 + fR*8 + fb];
      __syncthreads();
      if (tid < 24){
        float zi = zbuf[tid], zf = zbuf[24 + tid], zg = zbuf[48 + tid], zo = zbuf[72 + tid];
        c1r = sigm(zf)*c1r + sigm(zi)*tanhf(zg);
        float hh = sigm(zo)*tanhf(c1r);
        cstore(&xn[(wg*3 + (tid >> 3))*8 + (tid & 7)], hh);
      }
      ++bar; gbar(sy, bar);
    }

    // ---- stage B: gates2 = h1n @ wih2.T + h2 @ whh2.T + b ; cell2 ----
    {
      for (int idx = tid; idx < 6144; idx += 256){   // [xn | h2c] = 1536*8/2 u64
        const float* src = (idx < 3072) ? (xn + 2*idx) : (h2c + 2*idx - 6144);
        float a, b; cload64(src, a, b);
        int k = idx >> 2, p = (idx & 3) << 1;
        xs[p*SB + k]       = a;
        xs[(p + 1)*SB + k] = b;
      }
      __syncthreads();
      float acc[3][8];
      #pragma unroll
      for (int u = 0; u < 3; ++u)
        #pragma unroll
        for (int j = 0; j < 8; ++j) acc[u][j] = 0.f;
      #pragma unroll
      for (int ki = 0; ki < 24; ++ki){
        int k = l + (ki << 6);
        float x0 = xs[k],        x1 = xs[SB + k],   x2 = xs[2*SB + k], x3 = xs[3*SB + k];
        float x4 = xs[4*SB + k], x5 = xs[5*SB + k], x6 = xs[6*SB + k], x7 = xs[7*SB + k];
        #pragma unroll
        for (int u = 0; u < 3; ++u){
          float w = wB[ki][u];
          acc[u][0] = fmaf(w, x0, acc[u][0]);
          acc[u][1] = fmaf(w, x1, acc[u][1]);
          acc[u][2] = fmaf(w, x2, acc[u][2]);
          acc[u][3] = fmaf(w, x3, acc[u][3]);
          acc[u][4] = fmaf(w, x4, acc[u][4]);
          acc[u][5] = fmaf(w, x5, acc[u][5]);
          acc[u][6] = fmaf(w, x6, acc[u][6]);
          acc[u][7] = fmaf(w, x7, acc[u][7]);
        }
      }
      #pragma unroll
      for (int u = 0; u < 3; ++u)
        #pragma unroll
        for (int j = 0; j < 8; ++j){
          float s = acc[u][j];
          s += __shfl_xor(s, 1);  s += __shfl_xor(s, 2);  s += __shfl_xor(s, 4);
          s += __shfl_xor(s, 8);  s += __shfl_xor(s, 16); s += __shfl_xor(s, 32);
          if (l == 0) zbuf[wv*24 + u*8 + j] = s;
        }
      __syncthreads();
      if (tid < 96)
        zbuf[tid] += b2r;
      __syncthreads();
      if (tid < 24){
        float zi = zbuf[tid], zf = zbuf[24 + tid], zg = zbuf[48 + tid], zo = zbuf[72 + tid];
        c2r = sigm(zf)*c2r + sigm(zi)*tanhf(zg);
        float hh = sigm(zo)*tanhf(c2r);
        cstore(&h2n[(wg*3 + (tid >> 3))*8 + (tid & 7)], hh);
      }
      ++bar; gbar(sy, bar);
    }

    // ---- stage C: logits for pitch wg; argmax -> emb for next step ----
    if (wg < 88){
      for (int idx = tid; idx < 3072; idx += 256){   // h2n = 768*8/2 u64
        float a, b; cload64(h2n + 2*idx, a, b);
        int k = idx >> 2, p = (idx & 3) << 1;
        xs[p*SC + k]       = a;
        xs[(p + 1)*SC + k] = b;
      }
      __syncthreads();
      float acc[5][8];
      #pragma unroll
      for (int s = 0; s < 5; ++s)
        #pragma unroll
        for (int j = 0; j < 8; ++j) acc[s][j] = 0.f;
      #pragma unroll
      for (int kc = 0; kc < 3; ++kc){
        int k = tid + (kc << 8);
        float x0 = xs[k],        x1 = xs[SC + k],   x2 = xs[2*SC + k], x3 = xs[3*SC + k];
        float x4 = xs[4*SC + k], x5 = xs[5*SC + k], x6 = xs[6*SC + k], x7 = xs[7*SC + k];
        #pragma unroll
        for (int s = 0; s < 5; ++s){
          float w = wC[kc][s];
          acc[s][0] = fmaf(w, x0, acc[s][0]);
          acc[s][1] = fmaf(w, x1, acc[s][1]);
          acc[s][2] = fmaf(w, x2, acc[s][2]);
          acc[s][3] = fmaf(w, x3, acc[s][3]);
          acc[s][4] = fmaf(w, x4, acc[s][4]);
          acc[s][5] = fmaf(w, x5, acc[s][5]);
          acc[s][6] = fmaf(w, x6, acc[s][6]);
          acc[s][7] = fmaf(w, x7, acc[s][7]);
        }
      }
      #pragma unroll
      for (int s = 0; s < 5; ++s)
        #pragma unroll
        for (int j = 0; j < 8; ++j){
          float v = acc[s][j];
          v += __shfl_xor(v, 1);  v += __shfl_xor(v, 2);  v += __shfl_xor(v, 4);
          v += __shfl_xor(v, 8);  v += __shfl_xor(v, 16); v += __shfl_xor(v, 32);
          if (l == 0) red2[(s*8 + j)*4 + wv] = v;
        }
      __syncthreads();
      if (tid < 40){
        float sum = red2[tid*4] + red2[tid*4 + 1] + red2[tid*4 + 2] + red2[tid*4 + 3] + pbr;
        int s = tid >> 3, bb = tid & 7;
        out[bb*225280 + t*440 + wg*5 + s] = sum;
        zbuf[tid] = sum;
      }
      __syncthreads();
      if (tid < 8){
        float best = zbuf[tid]; int bs = 0;
        #pragma unroll
        for (int s = 1; s < 5; ++s){
          float v = zbuf[s*8 + tid];
          if (v > best){ best = v; bs = s; }   // first max wins (jnp.argmax)
        }
        cstore(&xn[(768 + wg*2)*8 + tid],     embw[bs*2]);
        cstore(&xn[(768 + wg*2 + 1)*8 + tid], embw[bs*2 + 1]);
      }
    }
    ++bar; gbar(sy, bar);
  }
}

extern "C" void kernel_launch(void* const* d_in, const int* in_sizes, int n_in,
                              void* d_out, int out_size, void* d_ws, size_t ws_size,
                              hipStream_t stream)
{
  (void)in_sizes; (void)n_in; (void)out_size; (void)ws_size;
  const float* mel  = (const float*)d_in[0];
  const float* w1   = (const float*)d_in[1];
  const float* b1   = (const float*)d_in[2];
  const float* g1   = (const float*)d_in[3];
  const float* be1  = (const float*)d_in[4];
  const float* m1   = (const float*)d_in[5];
  const float* v1   = (const float*)d_in[6];
  const float* w2   = (const float*)d_in[7];
  const float* b2   = (const float*)d_in[8];
  const float* g2   = (const float*)d_in[9];
  const float* be2  = (const float*)d_in[10];
  const float* m2   = (const float*)d_in[11];
  const float* v2   = (const float*)d_in[12];
  const float* w3   = (const float*)d_in[13];
  const float* b3   = (const float*)d_in[14];
  const float* g3   = (const float*)d_in[15];
  const float* be3  = (const float*)d_in[16];
  const float* m3   = (const float*)d_in[17];
  const float* v3   = (const float*)d_in[18];
  const float* fcw  = (const float*)d_in[19];
  const float* fcb  = (const float*)d_in[20];
  const float* wih1 = (const float*)d_in[21];
  const float* whh1 = (const float*)d_in[22];
  const float* bih1 = (const float*)d_in[23];
  const float* bhh1 = (const float*)d_in[24];
  const float* wih2 = (const float*)d_in[25];
  const float* whh2 = (const float*)d_in[26];
  const float* bih2 = (const float*)d_in[27];
  const float* bhh2 = (const float*)d_in[28];
  const float* postw= (const float*)d_in[29];
  const float* postb= (const float*)d_in[30];
  const float* embw = (const float*)d_in[31];

  float* ws    = (float*)d_ws;
  float* c3p   = ws + WS_C3;
  float* c2ch  = ws + WS_C2CH;
  float* ac    = ws + WS_AC;
  float* A1    = ws + WS_A1;
  float* st    = ws + WS_ST;
  float* xbuf  = st;
  float* h2b   = st + 15104;
  unsigned* sy = (unsigned*)(st + 27392);
  float* outp  = (float*)d_out;

  // zero recurrent state + barrier counters
  hipMemsetAsync(st, 0, 27648 * sizeof(float), stream);

  for (int c = 0; c < 4; ++c){
    int t0 = c * 128;
    conv2f_k<<<dim3(8*130), dim3(256), 0, stream>>>(
        mel, w1, b1, g1, be1, m1, v1, w2, b2, g2, be2, m2, v2, c2ch, t0);
    conv3_k<<<dim3(8*128), dim3(256), 0, stream>>>(
        c2ch, w3, b3, g3, be3, m3, v3, c3p, t0);
  }
  gemm_fc_k<<<dim3(32, 6), dim3(256), 0, stream>>>(c3p, fcw, fcb, ac);
  gemm_a1_k<<<dim3(32, 24), dim3(256), 0, stream>>>(ac, wih1, bih1, bhh1, A1);

  rec_k<<<dim3(256), dim3(256), 0, stream>>>(
      A1, whh1, wih1, wih2, whh2, bih2, bhh2, postw, postb, embw,
      xbuf, h2b, sy, outp);
}

// Round 6
// 24010.036 us; speedup vs baseline: 1.3154x; 1.0664x over previous
//
#include <hip/hip_runtime.h>
#include <math.h>

// ---------------- ws layout (float offsets), total ~119.3 MiB ----------------
#define WS_C3   0u
#define WS_C2CH 22413312u
#define WS_AC   28104192u
#define WS_A1   0u
#define WS_ST   31249920u

__device__ __forceinline__ float sigm(float x){ return 1.0f / (1.0f + expf(-x)); }

// Fine-grained coherent access (sc0 sc1): bypasses L1/L2, served at the
// coherence point — cross-XCD visible without cache flushes.
__device__ __forceinline__ void cstore(float* p, float v){
  union { float f; unsigned u; } c; c.f = v;
  __hip_atomic_store((unsigned*)p, c.u, __ATOMIC_RELAXED,
                     __HIP_MEMORY_SCOPE_SYSTEM);
}
__device__ __forceinline__ void cload64(const float* p, float& a, float& b){
  unsigned long long u = __hip_atomic_load((const unsigned long long*)p,
                          __ATOMIC_RELAXED, __HIP_MEMORY_SCOPE_SYSTEM);
  union { unsigned long long u; float f[2]; } c; c.u = u;
  a = c.f[0]; b = c.f[1];
}
__device__ __forceinline__ unsigned cloadu(const unsigned* p){
  return __hip_atomic_load(p, __ATOMIC_RELAXED, __HIP_MEMORY_SCOPE_SYSTEM);
}

// Contention-free grid barrier: arrival = store to own slot (no RMW!),
// wg 255 wave 0 polls all 256 slots (4/lane), then broadcasts via flag sy[0].
// Monotonic bar ordinal; slots sy[16..272). Entry __syncthreads drains
// vmcnt(0) so all coherent data stores are at the coherence point before the
// arrival store issues.
__device__ __forceinline__ void gbar(unsigned* sy, unsigned bar, int wg){
  __syncthreads();
  if (threadIdx.x == 0)
    __hip_atomic_store(&sy[16 + wg], bar, __ATOMIC_RELAXED,
                       __HIP_MEMORY_SCOPE_SYSTEM);
  if (wg == 255 && threadIdx.x < 64){
    const int l = threadIdx.x;
    for (;;){
      unsigned m0 = cloadu(&sy[16 + 4*l + 0]);
      unsigned m1 = cloadu(&sy[16 + 4*l + 1]);
      unsigned m2 = cloadu(&sy[16 + 4*l + 2]);
      unsigned m3 = cloadu(&sy[16 + 4*l + 3]);
      unsigned a = m0 < m1 ? m0 : m1;
      unsigned b = m2 < m3 ? m2 : m3;
      unsigned mn = a < b ? a : b;
      if (__all(mn >= bar)) break;
      __builtin_amdgcn_s_sleep(1);
    }
    if (l == 0)
      __hip_atomic_store(&sy[0], bar, __ATOMIC_RELAXED,
                         __HIP_MEMORY_SCOPE_SYSTEM);
  }
  if (wg != 255 && threadIdx.x == 0){
    while (cloadu(&sy[0]) < bar)
      __builtin_amdgcn_s_sleep(1);
  }
  __syncthreads();
}

// ------- conv2f: fused conv1+bn1+relu -> conv2+bn2+relu+pool(1,2) -------
__global__ __launch_bounds__(256) void conv2f_k(
    const float* __restrict__ mel, const float* __restrict__ w1,
    const float* __restrict__ b1, const float* __restrict__ g1,
    const float* __restrict__ be1, const float* __restrict__ m1,
    const float* __restrict__ v1,
    const float* __restrict__ w2, const float* __restrict__ b2,
    const float* __restrict__ g2, const float* __restrict__ be2,
    const float* __restrict__ m2, const float* __restrict__ v2,
    float* __restrict__ c2ch, int t0)
{
  __shared__ float act[3*8*240];
  __shared__ float w2s[48*8*12];
  __shared__ float mel5[5*240];
  __shared__ float w1s[48*12];
  __shared__ float sc1[48], sh1[48], sc2[48], sh2[48];
  int tid = threadIdx.x;
  int b = blockIdx.x / 130, lt = blockIdx.x - b*130;
  int t = t0 - 1 + lt;

  int fg = tid % 29, ocg = tid / 29;
  int f0 = fg * 8, oc0 = ocg * 6;

  if (t < 0 || t > 511){
    if (tid < 232){
      for (int o = 0; o < 6; ++o)
        for (int jj = 0; jj < 4; ++jj){
          int fp = fg*4 + jj;
          if (fp < 114)
            c2ch[((b*48 + oc0 + o)*130 + lt)*114 + fp] = 0.f;
        }
    }
    return;
  }

  for (int idx = tid; idx < 5*240; idx += 256){
    int rr = idx / 240, w = idx - rr*240;
    int tt = t + rr - 2, f = w - 2;
    mel5[idx] = (tt >= 0 && tt < 512 && f >= 0 && f < 229)
                ? mel[(b*512 + tt)*229 + f] : 0.f;
  }
  for (int idx = tid; idx < 48*12; idx += 256){
    int c = idx / 12, q = idx - c*12;
    int kh = q >> 2, kw = q & 3;
    w1s[idx] = (kw < 3) ? w1[c*9 + kh*3 + kw] : 0.f;
  }
  if (tid < 48){
    float s1 = g1[tid] / sqrtf(v1[tid] + 1e-5f);
    sc1[tid] = s1; sh1[tid] = be1[tid] + (b1[tid] - m1[tid]) * s1;
    float s2 = g2[tid] / sqrtf(v2[tid] + 1e-5f);
    sc2[tid] = s2; sh2[tid] = be2[tid] + (b2[tid] - m2[tid]) * s2;
  }

  float acc[6][8];
  #pragma unroll
  for (int o = 0; o < 6; ++o)
    #pragma unroll
    for (int j = 0; j < 8; ++j) acc[o][j] = 0.f;

  for (int ch = 0; ch < 6; ++ch){
    int ci0 = ch * 8;
    __syncthreads();
    for (int idx = tid; idx < 3*8*240; idx += 256){
      int rr = idx / 1920;
      int rem = idx - rr*1920;
      int ci = rem / 240, w = rem - ci*240;
      int tt = t + rr - 1, f = w - 1;
      float val = 0.f;
      if (tt >= 0 && tt < 512 && f >= 0 && f < 229){
        int cg = ci0 + ci;
        float a = 0.f;
        #pragma unroll
        for (int dh = 0; dh < 3; ++dh){
          const float* mr = &mel5[(rr + dh)*240 + w];
          a = fmaf(mr[0], w1s[cg*12 + dh*4 + 0], a);
          a = fmaf(mr[1], w1s[cg*12 + dh*4 + 1], a);
          a = fmaf(mr[2], w1s[cg*12 + dh*4 + 2], a);
        }
        a = a * sc1[cg] + sh1[cg];
        val = a > 0.f ? a : 0.f;
      }
      act[idx] = val;
    }
    for (int idx = tid; idx < 48*8*12; idx += 256){
      int oc = idx / 96;
      int rem = idx - oc*96;
      int ci = rem / 12, q = rem - ci*12;
      int kh = q >> 2, kw = q & 3;
      w2s[idx] = (kw < 3) ? w2[(oc*48 + ci0 + ci)*9 + kh*3 + kw] : 0.f;
    }
    __syncthreads();
    if (tid < 232){
      for (int ci = 0; ci < 8; ++ci){
        #pragma unroll
        for (int kh = 0; kh < 3; ++kh){
          const float* ap = &act[(kh*8 + ci)*240 + f0];
          float4 A0 = *(const float4*)(ap);
          float4 A1v = *(const float4*)(ap + 4);
          float4 A2 = *(const float4*)(ap + 8);
          float L[12] = {A0.x,A0.y,A0.z,A0.w,A1v.x,A1v.y,A1v.z,A1v.w,A2.x,A2.y,A2.z,A2.w};
          #pragma unroll
          for (int o = 0; o < 6; ++o){
            float4 wv = *(const float4*)&w2s[((oc0 + o)*8 + ci)*12 + kh*4];
            #pragma unroll
            for (int j = 0; j < 8; ++j)
              acc[o][j] = fmaf(L[j+2], wv.z, fmaf(L[j+1], wv.y, fmaf(L[j], wv.x, acc[o][j])));
          }
        }
      }
    }
  }
  __syncthreads();
  if (tid < 232){
    #pragma unroll
    for (int o = 0; o < 6; ++o){
      int oc = oc0 + o;
      float s = sc2[oc], hs = sh2[oc];
      #pragma unroll
      for (int jj = 0; jj < 4; ++jj){
        int fp = fg*4 + jj;
        if (fp < 114){
          float v0 = acc[o][2*jj] * s + hs;   v0 = v0 > 0.f ? v0 : 0.f;
          float v1 = acc[o][2*jj+1] * s + hs; v1 = v1 > 0.f ? v1 : 0.f;
          c2ch[((b*48 + oc)*130 + lt)*114 + fp] = v0 > v1 ? v0 : v1;
        }
      }
    }
  }
}

// ------- conv3 (48->96) + bn + relu + pool(1,2) -------
__global__ __launch_bounds__(256) void conv3_k(
    const float* __restrict__ c2ch, const float* __restrict__ w3,
    const float* __restrict__ b3, const float* __restrict__ g3,
    const float* __restrict__ be3, const float* __restrict__ m3,
    const float* __restrict__ v3, float* __restrict__ c3p, int t0)
{
  __shared__ float act[3*8*128];
  __shared__ float w3s[96*8*12];
  __shared__ float sc[96], sh[96];
  int tid = threadIdx.x;
  int b = blockIdx.x >> 7, tl = blockIdx.x & 127;
  int t = t0 + tl;
  if (tid < 96){
    float s = g3[tid] / sqrtf(v3[tid] + 1e-5f);
    sc[tid] = s; sh[tid] = be3[tid] + (b3[tid] - m3[tid]) * s;
  }
  int fg = tid % 15, ocg = tid / 15;
  int f0 = fg * 8, oc0 = ocg * 6;
  float acc[6][8];
  #pragma unroll
  for (int o = 0; o < 6; ++o)
    #pragma unroll
    for (int j = 0; j < 8; ++j) acc[o][j] = 0.f;

  for (int ch = 0; ch < 6; ++ch){
    int ci0 = ch * 8;
    __syncthreads();
    for (int idx = tid; idx < 3*8*128; idx += 256){
      int rr = idx >> 10;
      int rem = idx & 1023;
      int ci = rem >> 7, w = rem & 127;
      int lt = tl + rr;
      int f = w - 1;
      float val = 0.f;
      if (f >= 0 && f < 114)
        val = c2ch[((b*48 + ci0 + ci)*130 + lt)*114 + f];
      act[idx] = val;
    }
    for (int idx = tid; idx < 96*8*12; idx += 256){
      int oc = idx / 96;
      int rem = idx - oc*96;
      int ci = rem / 12, q = rem - ci*12;
      int kh = q >> 2, kw = q & 3;
      w3s[idx] = (kw < 3) ? w3[(oc*48 + ci0 + ci)*9 + kh*3 + kw] : 0.f;
    }
    __syncthreads();
    if (tid < 240){
      for (int ci = 0; ci < 8; ++ci){
        #pragma unroll
        for (int kh = 0; kh < 3; ++kh){
          const float* ap = &act[(kh*8 + ci)*128 + f0];
          float4 A0 = *(const float4*)(ap);
          float4 A1v = *(const float4*)(ap + 4);
          float4 A2 = *(const float4*)(ap + 8);
          float L[12] = {A0.x,A0.y,A0.z,A0.w,A1v.x,A1v.y,A1v.z,A1v.w,A2.x,A2.y,A2.z,A2.w};
          #pragma unroll
          for (int o = 0; o < 6; ++o){
            float4 wv = *(const float4*)&w3s[((oc0 + o)*8 + ci)*12 + kh*4];
            #pragma unroll
            for (int j = 0; j < 8; ++j)
              acc[o][j] = fmaf(L[j+2], wv.z, fmaf(L[j+1], wv.y, fmaf(L[j], wv.x, acc[o][j])));
          }
        }
      }
    }
  }
  __syncthreads();
  if (tid < 240){
    #pragma unroll
    for (int o = 0; o < 6; ++o){
      int oc = oc0 + o;
      float s = sc[oc], hs = sh[oc];
      #pragma unroll
      for (int jj = 0; jj < 4; ++jj){
        int fp = fg*4 + jj;
        if (fp < 57){
          float v0 = acc[o][2*jj] * s + hs;   v0 = v0 > 0.f ? v0 : 0.f;
          float v1 = acc[o][2*jj+1] * s + hs; v1 = v1 > 0.f ? v1 : 0.f;
          c3p[((b*96 + oc)*512 + t)*57 + fp] = v0 > v1 ? v0 : v1;
        }
      }
    }
  }
}

// ------- GEMM: acoustic = conv_feat @ fc_w.T + fc_b -------
__global__ __launch_bounds__(256) void gemm_fc_k(
    const float* __restrict__ c3p, const float* __restrict__ fcw,
    const float* __restrict__ fcb, float* __restrict__ ac)
{
  __shared__ float As[16*132];
  __shared__ float Bs[16*132];
  int tid = threadIdx.x;
  int m0 = blockIdx.x * 128, n0 = blockIdx.y * 128;
  int tm = (tid & 15) * 8, tn = (tid >> 4) * 8;
  float acc[8][8];
  #pragma unroll
  for (int i = 0; i < 8; ++i)
    #pragma unroll
    for (int j = 0; j < 8; ++j) acc[i][j] = 0.f;

  for (int k0 = 0; k0 < 5472; k0 += 16){
    __syncthreads();
    #pragma unroll
    for (int i = 0; i < 8; ++i){
      int idx = i*256 + tid;
      int k = idx & 15, mm = idx >> 4;
      int gk = k0 + k;
      int ci = (gk * 36793) >> 21;
      int f  = gk - ci*57;
      int gm = m0 + mm;
      int bb = gm >> 9, tt = gm & 511;
      As[k*132 + mm] = c3p[((bb*96 + ci)*512 + tt)*57 + f];
      Bs[k*132 + mm] = fcw[(n0 + mm)*5472 + gk];
    }
    __syncthreads();
    #pragma unroll
    for (int k = 0; k < 16; ++k){
      const float* arow = &As[k*132 + tm];
      const float* brow = &Bs[k*132 + tn];
      float4 a0 = *(const float4*)arow, a1 = *(const float4*)(arow + 4);
      float4 b0 = *(const float4*)brow, b1 = *(const float4*)(brow + 4);
      float av[8] = {a0.x,a0.y,a0.z,a0.w,a1.x,a1.y,a1.z,a1.w};
      float bv[8] = {b0.x,b0.y,b0.z,b0.w,b1.x,b1.y,b1.z,b1.w};
      #pragma unroll
      for (int i = 0; i < 8; ++i)
        #pragma unroll
        for (int j = 0; j < 8; ++j)
          acc[i][j] = fmaf(av[i], bv[j], acc[i][j]);
    }
  }
  #pragma unroll
  for (int i = 0; i < 8; ++i){
    int gm = m0 + tm + i;
    #pragma unroll
    for (int j = 0; j < 8; ++j){
      int gn = n0 + tn + j;
      ac[gm*768 + gn] = acc[i][j] + fcb[gn];
    }
  }
}

// ------- GEMM: A1[t][row][b] = acoustic @ wih1[:, :768].T + bih1+bhh1 -------
__global__ __launch_bounds__(256) void gemm_a1_k(
    const float* __restrict__ ac, const float* __restrict__ wih1,
    const float* __restrict__ bih1, const float* __restrict__ bhh1,
    float* __restrict__ A1)
{
  __shared__ float As[16*132];
  __shared__ float Bs[16*132];
  int tid = threadIdx.x;
  int m0 = blockIdx.x * 128, n0 = blockIdx.y * 128;
  int tm = (tid & 15) * 8, tn = (tid >> 4) * 8;
  float acc[8][8];
  #pragma unroll
  for (int i = 0; i < 8; ++i)
    #pragma unroll
    for (int j = 0; j < 8; ++j) acc[i][j] = 0.f;

  for (int k0 = 0; k0 < 768; k0 += 16){
    __syncthreads();
    #pragma unroll
    for (int i = 0; i < 8; ++i){
      int idx = i*256 + tid;
      int k = idx & 15, mm = idx >> 4;
      int gk = k0 + k;
      As[k*132 + mm] = ac[(m0 + mm)*768 + gk];
      Bs[k*132 + mm] = wih1[(n0 + mm)*944 + gk];
    }
    __syncthreads();
    #pragma unroll
    for (int k = 0; k < 16; ++k){
      const float* arow = &As[k*132 + tm];
      const float* brow = &Bs[k*132 + tn];
      float4 a0 = *(const float4*)arow, a1 = *(const float4*)(arow + 4);
      float4 b0 = *(const float4*)brow, b1 = *(const float4*)(brow + 4);
      float av[8] = {a0.x,a0.y,a0.z,a0.w,a1.x,a1.y,a1.z,a1.w};
      float bv[8] = {b0.x,b0.y,b0.z,b0.w,b1.x,b1.y,b1.z,b1.w};
      #pragma unroll
      for (int i = 0; i < 8; ++i)
        #pragma unroll
        for (int j = 0; j < 8; ++j)
          acc[i][j] = fmaf(av[i], bv[j], acc[i][j]);
    }
  }
  #pragma unroll
  for (int i = 0; i < 8; ++i){
    int gm = m0 + tm + i;
    int tt = gm & 511, bb = gm >> 9;
    #pragma unroll
    for (int j = 0; j < 8; ++j){
      int gn = n0 + tn + j;
      A1[tt*24576 + gn*8 + bb] = acc[i][j] + bih1[gn] + bhh1[gn];
    }
  }
}

// ---------------- persistent recurrent kernel ----------------
// Strides ≡ 4 (mod 32): staging writes (k = tid>>2, p = (tid&3)*2) land on
// banks k + {0,8,16,24} → exactly 2-way (free). Persistent h2s holds h2(t-1)
// locally (staged by ALL WGs in stage C), so stage B stages only h1.
#define SA 948
#define S2 772
__global__ __launch_bounds__(256, 1) void rec_k(
    const float* __restrict__ A1,
    const float* __restrict__ whh1, const float* __restrict__ wih1,
    const float* __restrict__ wih2, const float* __restrict__ whh2,
    const float* __restrict__ bih2, const float* __restrict__ bhh2,
    const float* __restrict__ postw, const float* __restrict__ postb,
    const float* __restrict__ embw,
    float* __restrict__ xbuf, float* __restrict__ h2b,
    unsigned* __restrict__ sy, float* __restrict__ out)
{
  const int wg = blockIdx.x, tid = threadIdx.x;
  const int wv = tid >> 6, l = tid & 63;
  __shared__ float xs[8*SA];     // 30.3 KB staging (stage A is largest: 944)
  __shared__ float h2s[8*S2];    // 24.7 KB persistent h2(t-1), b-major planes
  __shared__ float zbuf[96];
  __shared__ float red2[160];

  float wA[15][3];
  float wB[24][3];
  float wC[3][5];
  {
    int Rb = wv*768 + wg*3;
    #pragma unroll
    for (int ki = 0; ki < 15; ++ki){
      int k = l + (ki << 6);
      #pragma unroll
      for (int u = 0; u < 3; ++u){
        float w = 0.f;
        if (k < 768) w = whh1[(Rb + u)*768 + k];
        else if (k < 944) w = wih1[(Rb + u)*944 + k];
        wA[ki][u] = w;
      }
    }
    #pragma unroll
    for (int ki = 0; ki < 24; ++ki){
      int k = l + (ki << 6);
      #pragma unroll
      for (int u = 0; u < 3; ++u)
        wB[ki][u] = (k < 768) ? wih2[(Rb + u)*768 + k] : whh2[(Rb + u)*768 + k - 768];
    }
  }
  if (wg < 88){
    #pragma unroll
    for (int kc = 0; kc < 3; ++kc)
      #pragma unroll
      for (int s = 0; s < 5; ++s)
        wC[kc][s] = postw[(wg*5 + s)*768 + tid + (kc << 8)];
  }
  float b2r = 0.f; int fR = 0, fb = 0;
  if (tid < 96){
    int g = tid / 24, rem = tid - g*24;
    int u = rem >> 3; fb = rem & 7;
    fR = g*768 + wg*3 + u;
    b2r = bih2[fR] + bhh2[fR];
  }
  float pbr = (wg < 88 && tid < 40) ? postb[wg*5 + (tid >> 3)] : 0.f;
  float c1r = 0.f, c2r = 0.f;

  // init: h2(−1) = 0 locally; emb(prev=0) into xbuf[0]'s emb region (wg 0)
  for (int idx = tid; idx < 8*S2; idx += 256) h2s[idx] = 0.f;
  if (wg == 0){
    for (int idx = tid; idx < 1408; idx += 256){
      int e = idx >> 3, bb = idx & 7;
      cstore(&xbuf[(768 + e)*8 + bb], embw[e & 1]);
    }
  }
  unsigned bar = 1;
  gbar(sy, bar, wg);

  for (int t = 0; t < 512; ++t){
    const int cur = t & 1, nxt = cur ^ 1;
    float* xc  = xbuf + cur * 7552;
    float* xn  = xbuf + nxt * 7552;
    float* h2n = h2b + nxt * 6144;

    // prefetch A1[t] (regular cached load — off the barrier path)
    float a1v = 0.f;
    if (tid < 96) a1v = A1[t*24576 + fR*8 + fb];

    // ---- stage A: gates1 = A1[t] + [h1,emb] @ [whh1|We].T ; cell1 ----
    {
      for (int idx = tid; idx < 3776; idx += 256){   // 944*8/2 u64 words
        float a, b; cload64(xc + 2*idx, a, b);
        int k = idx >> 2, p = (idx & 3) << 1;
        xs[p*SA + k]       = a;
        xs[(p + 1)*SA + k] = b;
      }
      __syncthreads();
      float acc[3][8];
      #pragma unroll
      for (int u = 0; u < 3; ++u)
        #pragma unroll
        for (int j = 0; j < 8; ++j) acc[u][j] = 0.f;
      #pragma unroll
      for (int ki = 0; ki < 15; ++ki){
        int k = l + (ki << 6);
        if (k < 944){
          float x0 = xs[k],        x1 = xs[SA + k],   x2 = xs[2*SA + k], x3 = xs[3*SA + k];
          float x4 = xs[4*SA + k], x5 = xs[5*SA + k], x6 = xs[6*SA + k], x7 = xs[7*SA + k];
          #pragma unroll
          for (int u = 0; u < 3; ++u){
            float w = wA[ki][u];
            acc[u][0] = fmaf(w, x0, acc[u][0]);
            acc[u][1] = fmaf(w, x1, acc[u][1]);
            acc[u][2] = fmaf(w, x2, acc[u][2]);
            acc[u][3] = fmaf(w, x3, acc[u][3]);
            acc[u][4] = fmaf(w, x4, acc[u][4]);
            acc[u][5] = fmaf(w, x5, acc[u][5]);
            acc[u][6] = fmaf(w, x6, acc[u][6]);
            acc[u][7] = fmaf(w, x7, acc[u][7]);
          }
        }
      }
      #pragma unroll
      for (int u = 0; u < 3; ++u)
        #pragma unroll
        for (int j = 0; j < 8; ++j){
          float s = acc[u][j];
          s += __shfl_xor(s, 1);  s += __shfl_xor(s, 2);  s += __shfl_xor(s, 4);
          s += __shfl_xor(s, 8);  s += __shfl_xor(s, 16); s += __shfl_xor(s, 32);
          if (l == 0) zbuf[wv*24 + u*8 + j] = s;
        }
      __syncthreads();
      if (tid < 96)
        zbuf[tid] += a1v;
      __syncthreads();
      if (tid < 24){
        float zi = zbuf[tid], zf = zbuf[24 + tid], zg = zbuf[48 + tid], zo = zbuf[72 + tid];
        c1r = sigm(zf)*c1r + sigm(zi)*tanhf(zg);
        float hh = sigm(zo)*tanhf(c1r);
        cstore(&xn[(wg*3 + (tid >> 3))*8 + (tid & 7)], hh);
      }
      ++bar; gbar(sy, bar, wg);
    }

    // ---- stage B: gates2 = h1n @ wih2.T + h2(t-1)[LDS] @ whh2.T + b ----
    {
      for (int idx = tid; idx < 3072; idx += 256){   // h1n = 768*8/2 u64
        float a, b; cload64(xn + 2*idx, a, b);
        int k = idx >> 2, p = (idx & 3) << 1;
        xs[p*S2 + k]       = a;
        xs[(p + 1)*S2 + k] = b;
      }
      __syncthreads();
      float acc[3][8];
      #pragma unroll
      for (int u = 0; u < 3; ++u)
        #pragma unroll
        for (int j = 0; j < 8; ++j) acc[u][j] = 0.f;
      #pragma unroll
      for (int ki = 0; ki < 24; ++ki){
        float x0, x1, x2, x3, x4, x5, x6, x7;
        if (ki < 12){
          int k = l + (ki << 6);
          x0 = xs[k];        x1 = xs[S2 + k];   x2 = xs[2*S2 + k]; x3 = xs[3*S2 + k];
          x4 = xs[4*S2 + k]; x5 = xs[5*S2 + k]; x6 = xs[6*S2 + k]; x7 = xs[7*S2 + k];
        } else {
          int k = l + ((ki - 12) << 6);
          x0 = h2s[k];        x1 = h2s[S2 + k];   x2 = h2s[2*S2 + k]; x3 = h2s[3*S2 + k];
          x4 = h2s[4*S2 + k]; x5 = h2s[5*S2 + k]; x6 = h2s[6*S2 + k]; x7 = h2s[7*S2 + k];
        }
        #pragma unroll
        for (int u = 0; u < 3; ++u){
          float w = wB[ki][u];
          acc[u][0] = fmaf(w, x0, acc[u][0]);
          acc[u][1] = fmaf(w, x1, acc[u][1]);
          acc[u][2] = fmaf(w, x2, acc[u][2]);
          acc[u][3] = fmaf(w, x3, acc[u][3]);
          acc[u][4] = fmaf(w, x4, acc[u][4]);
          acc[u][5] = fmaf(w, x5, acc[u][5]);
          acc[u][6] = fmaf(w, x6, acc[u][6]);
          acc[u][7] = fmaf(w, x7, acc[u][7]);
        }
      }
      #pragma unroll
      for (int u = 0; u < 3; ++u)
        #pragma unroll
        for (int j = 0; j < 8; ++j){
          float s = acc[u][j];
          s += __shfl_xor(s, 1);  s += __shfl_xor(s, 2);  s += __shfl_xor(s, 4);
          s += __shfl_xor(s, 8);  s += __shfl_xor(s, 16); s += __shfl_xor(s, 32);
          if (l == 0) zbuf[wv*24 + u*8 + j] = s;
        }
      __syncthreads();
      if (tid < 96)
        zbuf[tid] += b2r;
      __syncthreads();
      if (tid < 24){
        float zi = zbuf[tid], zf = zbuf[24 + tid], zg = zbuf[48 + tid], zo = zbuf[72 + tid];
        c2r = sigm(zf)*c2r + sigm(zi)*tanhf(zg);
        float hh = sigm(zo)*tanhf(c2r);
        cstore(&h2n[(wg*3 + (tid >> 3))*8 + (tid & 7)], hh);
      }
      ++bar; gbar(sy, bar, wg);
    }

    // ---- stage C: ALL WGs stage h2n into h2s (persists for next stage B);
    //      wg<88 compute logits, argmax, emb ----
    {
      for (int idx = tid; idx < 3072; idx += 256){   // h2n = 768*8/2 u64
        float a, b; cload64(h2n + 2*idx, a, b);
        int k = idx >> 2, p = (idx & 3) << 1;
        h2s[p*S2 + k]       = a;
        h2s[(p + 1)*S2 + k] = b;
      }
      __syncthreads();
      if (wg < 88){
        float acc[5][8];
        #pragma unroll
        for (int s = 0; s < 5; ++s)
          #pragma unroll
          for (int j = 0; j < 8; ++j) acc[s][j] = 0.f;
        #pragma unroll
        for (int kc = 0; kc < 3; ++kc){
          int k = tid + (kc << 8);
          float x0 = h2s[k],        x1 = h2s[S2 + k],   x2 = h2s[2*S2 + k], x3 = h2s[3*S2 + k];
          float x4 = h2s[4*S2 + k], x5 = h2s[5*S2 + k], x6 = h2s[6*S2 + k], x7 = h2s[7*S2 + k];
          #pragma unroll
          for (int s = 0; s < 5; ++s){
            float w = wC[kc][s];
            acc[s][0] = fmaf(w, x0, acc[s][0]);
            acc[s][1] = fmaf(w, x1, acc[s][1]);
            acc[s][2] = fmaf(w, x2, acc[s][2]);
            acc[s][3] = fmaf(w, x3, acc[s][3]);
            acc[s][4] = fmaf(w, x4, acc[s][4]);
            acc[s][5] = fmaf(w, x5, acc[s][5]);
            acc[s][6] = fmaf(w, x6, acc[s][6]);
            acc[s][7] = fmaf(w, x7, acc[s][7]);
          }
        }
        #pragma unroll
        for (int s = 0; s < 5; ++s)
          #pragma unroll
          for (int j = 0; j < 8; ++j){
            float v = acc[s][j];
            v += __shfl_xor(v, 1);  v += __shfl_xor(v, 2);  v += __shfl_xor(v, 4);
            v += __shfl_xor(v, 8);  v += __shfl_xor(v, 16); v += __shfl_xor(v, 32);
            if (l == 0) red2[(s*8 + j)*4 + wv] = v;
          }
        __syncthreads();
        if (tid < 40){
          float sum = red2[tid*4] + red2[tid*4 + 1] + red2[tid*4 + 2] + red2[tid*4 + 3] + pbr;
          int s = tid >> 3, bb = tid & 7;
          out[bb*225280 + t*440 + wg*5 + s] = sum;
          zbuf[tid] = sum;
        }
        __syncthreads();
        if (tid < 8){
          float best = zbuf[tid]; int bs = 0;
          #pragma unroll
          for (int s = 1; s < 5; ++s){
            float v = zbuf[s*8 + tid];
            if (v > best){ best = v; bs = s; }   // first max wins (jnp.argmax)
          }
          cstore(&xn[(768 + wg*2)*8 + tid],     embw[bs*2]);
          cstore(&xn[(768 + wg*2 + 1)*8 + tid], embw[bs*2 + 1]);
        }
      }
      ++bar; gbar(sy, bar, wg);
    }
  }
}

extern "C" void kernel_launch(void* const* d_in, const int* in_sizes, int n_in,
                              void* d_out, int out_size, void* d_ws, size_t ws_size,
                              hipStream_t stream)
{
  (void)in_sizes; (void)n_in; (void)out_size; (void)ws_size;
  const float* mel  = (const float*)d_in[0];
  const float* w1   = (const float*)d_in[1];
  const float* b1   = (const float*)d_in[2];
  const float* g1   = (const float*)d_in[3];
  const float* be1  = (const float*)d_in[4];
  const float* m1   = (const float*)d_in[5];
  const float* v1   = (const float*)d_in[6];
  const float* w2   = (const float*)d_in[7];
  const float* b2   = (const float*)d_in[8];
  const float* g2   = (const float*)d_in[9];
  const float* be2  = (const float*)d_in[10];
  const float* m2   = (const float*)d_in[11];
  const float* v2   = (const float*)d_in[12];
  const float* w3   = (const float*)d_in[13];
  const float* b3   = (const float*)d_in[14];
  const float* g3   = (const float*)d_in[15];
  const float* be3  = (const float*)d_in[16];
  const float* m3   = (const float*)d_in[17];
  const float* v3   = (const float*)d_in[18];
  const float* fcw  = (const float*)d_in[19];
  const float* fcb  = (const float*)d_in[20];
  const float* wih1 = (const float*)d_in[21];
  const float* whh1 = (const float*)d_in[22];
  const float* bih1 = (const float*)d_in[23];
  const float* bhh1 = (const float*)d_in[24];
  const float* wih2 = (const float*)d_in[25];
  const float* whh2 = (const float*)d_in[26];
  const float* bih2 = (const float*)d_in[27];
  const float* bhh2 = (const float*)d_in[28];
  const float* postw= (const float*)d_in[29];
  const float* postb= (const float*)d_in[30];
  const float* embw = (const float*)d_in[31];

  float* ws    = (float*)d_ws;
  float* c3p   = ws + WS_C3;
  float* c2ch  = ws + WS_C2CH;
  float* ac    = ws + WS_AC;
  float* A1    = ws + WS_A1;
  float* st    = ws + WS_ST;
  float* xbuf  = st;
  float* h2b   = st + 15104;
  unsigned* sy = (unsigned*)(st + 27392);
  float* outp  = (float*)d_out;

  // zero recurrent state + barrier slots/flag (ws re-poisoned each launch)
  hipMemsetAsync(st, 0, 27904 * sizeof(float), stream);

  for (int c = 0; c < 4; ++c){
    int t0 = c * 128;
    conv2f_k<<<dim3(8*130), dim3(256), 0, stream>>>(
        mel, w1, b1, g1, be1, m1, v1, w2, b2, g2, be2, m2, v2, c2ch, t0);
    conv3_k<<<dim3(8*128), dim3(256), 0, stream>>>(
        c2ch, w3, b3, g3, be3, m3, v3, c3p, t0);
  }
  gemm_fc_k<<<dim3(32, 6), dim3(256), 0, stream>>>(c3p, fcw, fcb, ac);
  gemm_a1_k<<<dim3(32, 24), dim3(256), 0, stream>>>(ac, wih1, bih1, bhh1, A1);

  rec_k<<<dim3(256), dim3(256), 0, stream>>>(
      A1, whh1, wih1, wih2, whh2, bih2, bhh2, postw, postb, embw,
      xbuf, h2b, sy, outp);
}

// Round 7
// 22300.569 us; speedup vs baseline: 1.4162x; 1.0767x over previous
//
#include <hip/hip_runtime.h>
#include <math.h>

// ---------------- ws layout (float offsets), total ~119.4 MiB ----------------
#define WS_C3   0u
#define WS_C2CH 22413312u
#define WS_AC   28104192u
#define WS_A1   0u
#define WS_ST   31249920u

__device__ __forceinline__ float sigm(float x){ return 1.0f / (1.0f + expf(-x)); }

// Fine-grained coherent access (sc0 sc1): bypasses L1/L2, served at the
// coherence point — cross-XCD visible without cache flushes.
__device__ __forceinline__ void cstore(float* p, float v){
  union { float f; unsigned u; } c; c.f = v;
  __hip_atomic_store((unsigned*)p, c.u, __ATOMIC_RELAXED,
                     __HIP_MEMORY_SCOPE_SYSTEM);
}
__device__ __forceinline__ void cload64(const float* p, float& a, float& b){
  unsigned long long u = __hip_atomic_load((const unsigned long long*)p,
                          __ATOMIC_RELAXED, __HIP_MEMORY_SCOPE_SYSTEM);
  union { unsigned long long u; float f[2]; } c; c.u = u;
  a = c.f[0]; b = c.f[1];
}
__device__ __forceinline__ unsigned cloadu(const unsigned* p){
  return __hip_atomic_load(p, __ATOMIC_RELAXED, __HIP_MEMORY_SCOPE_SYSTEM);
}

// Fully distributed grid barrier — no address has more than ONE reader or
// concurrent-writer set that serializes:
//   arrival slots sy[16 + wg*16]   (256 lines, writer=wg, reader=wg255)
//   flag copies   sy[4112 + wg*16] (256 lines, writer=wg255, reader=wg)
// wg255 wave0 polls all 256 slots (4/lane), then ALL 256 threads of wg255
// store bar into the 256 flag lines; each other WG polls its own flag line.
#define SLOT 16
#define FLG  4112
__device__ __forceinline__ void gbar(unsigned* sy, unsigned bar, int wg){
  __syncthreads();   // drains vmcnt(0): all coherent data stores visible
  const int tid = threadIdx.x;
  if (tid == 0)
    __hip_atomic_store(&sy[SLOT + wg*16], bar, __ATOMIC_RELAXED,
                       __HIP_MEMORY_SCOPE_SYSTEM);
  if (wg == 255){
    if (tid < 64){
      for (;;){
        unsigned m0 = cloadu(&sy[SLOT + (4*tid + 0)*16]);
        unsigned m1 = cloadu(&sy[SLOT + (4*tid + 1)*16]);
        unsigned m2 = cloadu(&sy[SLOT + (4*tid + 2)*16]);
        unsigned m3 = cloadu(&sy[SLOT + (4*tid + 3)*16]);
        unsigned a = m0 < m1 ? m0 : m1;
        unsigned b = m2 < m3 ? m2 : m3;
        unsigned mn = a < b ? a : b;
        if (__all(mn >= bar)) break;
        __builtin_amdgcn_s_sleep(1);
      }
    }
    __syncthreads();   // orders poll completion before flag release
    __hip_atomic_store(&sy[FLG + tid*16], bar, __ATOMIC_RELAXED,
                       __HIP_MEMORY_SCOPE_SYSTEM);
  } else {
    if (tid == 0){
      while (cloadu(&sy[FLG + wg*16]) < bar)
        __builtin_amdgcn_s_sleep(1);
    }
  }
  __syncthreads();
}

// ------- conv2f: fused conv1+bn1+relu -> conv2+bn2+relu+pool(1,2) -------
__global__ __launch_bounds__(256) void conv2f_k(
    const float* __restrict__ mel, const float* __restrict__ w1,
    const float* __restrict__ b1, const float* __restrict__ g1,
    const float* __restrict__ be1, const float* __restrict__ m1,
    const float* __restrict__ v1,
    const float* __restrict__ w2, const float* __restrict__ b2,
    const float* __restrict__ g2, const float* __restrict__ be2,
    const float* __restrict__ m2, const float* __restrict__ v2,
    float* __restrict__ c2ch, int t0)
{
  __shared__ float act[3*8*240];
  __shared__ float w2s[48*8*12];
  __shared__ float mel5[5*240];
  __shared__ float w1s[48*12];
  __shared__ float sc1[48], sh1[48], sc2[48], sh2[48];
  int tid = threadIdx.x;
  int b = blockIdx.x / 130, lt = blockIdx.x - b*130;
  int t = t0 - 1 + lt;

  int fg = tid % 29, ocg = tid / 29;
  int f0 = fg * 8, oc0 = ocg * 6;

  if (t < 0 || t > 511){
    if (tid < 232){
      for (int o = 0; o < 6; ++o)
        for (int jj = 0; jj < 4; ++jj){
          int fp = fg*4 + jj;
          if (fp < 114)
            c2ch[((b*48 + oc0 + o)*130 + lt)*114 + fp] = 0.f;
        }
    }
    return;
  }

  for (int idx = tid; idx < 5*240; idx += 256){
    int rr = idx / 240, w = idx - rr*240;
    int tt = t + rr - 2, f = w - 2;
    mel5[idx] = (tt >= 0 && tt < 512 && f >= 0 && f < 229)
                ? mel[(b*512 + tt)*229 + f] : 0.f;
  }
  for (int idx = tid; idx < 48*12; idx += 256){
    int c = idx / 12, q = idx - c*12;
    int kh = q >> 2, kw = q & 3;
    w1s[idx] = (kw < 3) ? w1[c*9 + kh*3 + kw] : 0.f;
  }
  if (tid < 48){
    float s1 = g1[tid] / sqrtf(v1[tid] + 1e-5f);
    sc1[tid] = s1; sh1[tid] = be1[tid] + (b1[tid] - m1[tid]) * s1;
    float s2 = g2[tid] / sqrtf(v2[tid] + 1e-5f);
    sc2[tid] = s2; sh2[tid] = be2[tid] + (b2[tid] - m2[tid]) * s2;
  }

  float acc[6][8];
  #pragma unroll
  for (int o = 0; o < 6; ++o)
    #pragma unroll
    for (int j = 0; j < 8; ++j) acc[o][j] = 0.f;

  for (int ch = 0; ch < 6; ++ch){
    int ci0 = ch * 8;
    __syncthreads();
    for (int idx = tid; idx < 3*8*240; idx += 256){
      int rr = idx / 1920;
      int rem = idx - rr*1920;
      int ci = rem / 240, w = rem - ci*240;
      int tt = t + rr - 1, f = w - 1;
      float val = 0.f;
      if (tt >= 0 && tt < 512 && f >= 0 && f < 229){
        int cg = ci0 + ci;
        float a = 0.f;
        #pragma unroll
        for (int dh = 0; dh < 3; ++dh){
          const float* mr = &mel5[(rr + dh)*240 + w];
          a = fmaf(mr[0], w1s[cg*12 + dh*4 + 0], a);
          a = fmaf(mr[1], w1s[cg*12 + dh*4 + 1], a);
          a = fmaf(mr[2], w1s[cg*12 + dh*4 + 2], a);
        }
        a = a * sc1[cg] + sh1[cg];
        val = a > 0.f ? a : 0.f;
      }
      act[idx] = val;
    }
    for (int idx = tid; idx < 48*8*12; idx += 256){
      int oc = idx / 96;
      int rem = idx - oc*96;
      int ci = rem / 12, q = rem - ci*12;
      int kh = q >> 2, kw = q & 3;
      w2s[idx] = (kw < 3) ? w2[(oc*48 + ci0 + ci)*9 + kh*3 + kw] : 0.f;
    }
    __syncthreads();
    if (tid < 232){
      for (int ci = 0; ci < 8; ++ci){
        #pragma unroll
        for (int kh = 0; kh < 3; ++kh){
          const float* ap = &act[(kh*8 + ci)*240 + f0];
          float4 A0 = *(const float4*)(ap);
          float4 A1v = *(const float4*)(ap + 4);
          float4 A2 = *(const float4*)(ap + 8);
          float L[12] = {A0.x,A0.y,A0.z,A0.w,A1v.x,A1v.y,A1v.z,A1v.w,A2.x,A2.y,A2.z,A2.w};
          #pragma unroll
          for (int o = 0; o < 6; ++o){
            float4 wv = *(const float4*)&w2s[((oc0 + o)*8 + ci)*12 + kh*4];
            #pragma unroll
            for (int j = 0; j < 8; ++j)
              acc[o][j] = fmaf(L[j+2], wv.z, fmaf(L[j+1], wv.y, fmaf(L[j], wv.x, acc[o][j])));
          }
        }
      }
    }
  }
  __syncthreads();
  if (tid < 232){
    #pragma unroll
    for (int o = 0; o < 6; ++o){
      int oc = oc0 + o;
      float s = sc2[oc], hs = sh2[oc];
      #pragma unroll
      for (int jj = 0; jj < 4; ++jj){
        int fp = fg*4 + jj;
        if (fp < 114){
          float v0 = acc[o][2*jj] * s + hs;   v0 = v0 > 0.f ? v0 : 0.f;
          float v1 = acc[o][2*jj+1] * s + hs; v1 = v1 > 0.f ? v1 : 0.f;
          c2ch[((b*48 + oc)*130 + lt)*114 + fp] = v0 > v1 ? v0 : v1;
        }
      }
    }
  }
}

// ------- conv3 (48->96) + bn + relu + pool(1,2) -------
__global__ __launch_bounds__(256) void conv3_k(
    const float* __restrict__ c2ch, const float* __restrict__ w3,
    const float* __restrict__ b3, const float* __restrict__ g3,
    const float* __restrict__ be3, const float* __restrict__ m3,
    const float* __restrict__ v3, float* __restrict__ c3p, int t0)
{
  __shared__ float act[3*8*128];
  __shared__ float w3s[96*8*12];
  __shared__ float sc[96], sh[96];
  int tid = threadIdx.x;
  int b = blockIdx.x >> 7, tl = blockIdx.x & 127;
  int t = t0 + tl;
  if (tid < 96){
    float s = g3[tid] / sqrtf(v3[tid] + 1e-5f);
    sc[tid] = s; sh[tid] = be3[tid] + (b3[tid] - m3[tid]) * s;
  }
  int fg = tid % 15, ocg = tid / 15;
  int f0 = fg * 8, oc0 = ocg * 6;
  float acc[6][8];
  #pragma unroll
  for (int o = 0; o < 6; ++o)
    #pragma unroll
    for (int j = 0; j < 8; ++j) acc[o][j] = 0.f;

  for (int ch = 0; ch < 6; ++ch){
    int ci0 = ch * 8;
    __syncthreads();
    for (int idx = tid; idx < 3*8*128; idx += 256){
      int rr = idx >> 10;
      int rem = idx & 1023;
      int ci = rem >> 7, w = rem & 127;
      int lt = tl + rr;
      int f = w - 1;
      float val = 0.f;
      if (f >= 0 && f < 114)
        val = c2ch[((b*48 + ci0 + ci)*130 + lt)*114 + f];
      act[idx] = val;
    }
    for (int idx = tid; idx < 96*8*12; idx += 256){
      int oc = idx / 96;
      int rem = idx - oc*96;
      int ci = rem / 12, q = rem - ci*12;
      int kh = q >> 2, kw = q & 3;
      w3s[idx] = (kw < 3) ? w3[(oc*48 + ci0 + ci)*9 + kh*3 + kw] : 0.f;
    }
    __syncthreads();
    if (tid < 240){
      for (int ci = 0; ci < 8; ++ci){
        #pragma unroll
        for (int kh = 0; kh < 3; ++kh){
          const float* ap = &act[(kh*8 + ci)*128 + f0];
          float4 A0 = *(const float4*)(ap);
          float4 A1v = *(const float4*)(ap + 4);
          float4 A2 = *(const float4*)(ap + 8);
          float L[12] = {A0.x,A0.y,A0.z,A0.w,A1v.x,A1v.y,A1v.z,A1v.w,A2.x,A2.y,A2.z,A2.w};
          #pragma unroll
          for (int o = 0; o < 6; ++o){
            float4 wv = *(const float4*)&w3s[((oc0 + o)*8 + ci)*12 + kh*4];
            #pragma unroll
            for (int j = 0; j < 8; ++j)
              acc[o][j] = fmaf(L[j+2], wv.z, fmaf(L[j+1], wv.y, fmaf(L[j], wv.x, acc[o][j])));
          }
        }
      }
    }
  }
  __syncthreads();
  if (tid < 240){
    #pragma unroll
    for (int o = 0; o < 6; ++o){
      int oc = oc0 + o;
      float s = sc[oc], hs = sh[oc];
      #pragma unroll
      for (int jj = 0; jj < 4; ++jj){
        int fp = fg*4 + jj;
        if (fp < 57){
          float v0 = acc[o][2*jj] * s + hs;   v0 = v0 > 0.f ? v0 : 0.f;
          float v1 = acc[o][2*jj+1] * s + hs; v1 = v1 > 0.f ? v1 : 0.f;
          c3p[((b*96 + oc)*512 + t)*57 + fp] = v0 > v1 ? v0 : v1;
        }
      }
    }
  }
}

// ------- GEMM: acoustic = conv_feat @ fc_w.T + fc_b -------
__global__ __launch_bounds__(256) void gemm_fc_k(
    const float* __restrict__ c3p, const float* __restrict__ fcw,
    const float* __restrict__ fcb, float* __restrict__ ac)
{
  __shared__ float As[16*132];
  __shared__ float Bs[16*132];
  int tid = threadIdx.x;
  int m0 = blockIdx.x * 128, n0 = blockIdx.y * 128;
  int tm = (tid & 15) * 8, tn = (tid >> 4) * 8;
  float acc[8][8];
  #pragma unroll
  for (int i = 0; i < 8; ++i)
    #pragma unroll
    for (int j = 0; j < 8; ++j) acc[i][j] = 0.f;

  for (int k0 = 0; k0 < 5472; k0 += 16){
    __syncthreads();
    #pragma unroll
    for (int i = 0; i < 8; ++i){
      int idx = i*256 + tid;
      int k = idx & 15, mm = idx >> 4;
      int gk = k0 + k;
      int ci = (gk * 36793) >> 21;
      int f  = gk - ci*57;
      int gm = m0 + mm;
      int bb = gm >> 9, tt = gm & 511;
      As[k*132 + mm] = c3p[((bb*96 + ci)*512 + tt)*57 + f];
      Bs[k*132 + mm] = fcw[(n0 + mm)*5472 + gk];
    }
    __syncthreads();
    #pragma unroll
    for (int k = 0; k < 16; ++k){
      const float* arow = &As[k*132 + tm];
      const float* brow = &Bs[k*132 + tn];
      float4 a0 = *(const float4*)arow, a1 = *(const float4*)(arow + 4);
      float4 b0 = *(const float4*)brow, b1 = *(const float4*)(brow + 4);
      float av[8] = {a0.x,a0.y,a0.z,a0.w,a1.x,a1.y,a1.z,a1.w};
      float bv[8] = {b0.x,b0.y,b0.z,b0.w,b1.x,b1.y,b1.z,b1.w};
      #pragma unroll
      for (int i = 0; i < 8; ++i)
        #pragma unroll
        for (int j = 0; j < 8; ++j)
          acc[i][j] = fmaf(av[i], bv[j], acc[i][j]);
    }
  }
  #pragma unroll
  for (int i = 0; i < 8; ++i){
    int gm = m0 + tm + i;
    #pragma unroll
    for (int j = 0; j < 8; ++j){
      int gn = n0 + tn + j;
      ac[gm*768 + gn] = acc[i][j] + fcb[gn];
    }
  }
}

// ------- GEMM: A1[t][row][b] = acoustic @ wih1[:, :768].T + bih1+bhh1 -------
__global__ __launch_bounds__(256) void gemm_a1_k(
    const float* __restrict__ ac, const float* __restrict__ wih1,
    const float* __restrict__ bih1, const float* __restrict__ bhh1,
    float* __restrict__ A1)
{
  __shared__ float As[16*132];
  __shared__ float Bs[16*132];
  int tid = threadIdx.x;
  int m0 = blockIdx.x * 128, n0 = blockIdx.y * 128;
  int tm = (tid & 15) * 8, tn = (tid >> 4) * 8;
  float acc[8][8];
  #pragma unroll
  for (int i = 0; i < 8; ++i)
    #pragma unroll
    for (int j = 0; j < 8; ++j) acc[i][j] = 0.f;

  for (int k0 = 0; k0 < 768; k0 += 16){
    __syncthreads();
    #pragma unroll
    for (int i = 0; i < 8; ++i){
      int idx = i*256 + tid;
      int k = idx & 15, mm = idx >> 4;
      int gk = k0 + k;
      As[k*132 + mm] = ac[(m0 + mm)*768 + gk];
      Bs[k*132 + mm] = wih1[(n0 + mm)*944 + gk];
    }
    __syncthreads();
    #pragma unroll
    for (int k = 0; k < 16; ++k){
      const float* arow = &As[k*132 + tm];
      const float* brow = &Bs[k*132 + tn];
      float4 a0 = *(const float4*)arow, a1 = *(const float4*)(arow + 4);
      float4 b0 = *(const float4*)brow, b1 = *(const float4*)(brow + 4);
      float av[8] = {a0.x,a0.y,a0.z,a0.w,a1.x,a1.y,a1.z,a1.w};
      float bv[8] = {b0.x,b0.y,b0.z,b0.w,b1.x,b1.y,b1.z,b1.w};
      #pragma unroll
      for (int i = 0; i < 8; ++i)
        #pragma unroll
        for (int j = 0; j < 8; ++j)
          acc[i][j] = fmaf(av[i], bv[j], acc[i][j]);
    }
  }
  #pragma unroll
  for (int i = 0; i < 8; ++i){
    int gm = m0 + tm + i;
    int tt = gm & 511, bb = gm >> 9;
    #pragma unroll
    for (int j = 0; j < 8; ++j){
      int gn = n0 + tn + j;
      A1[tt*24576 + gn*8 + bb] = acc[i][j] + bih1[gn] + bhh1[gn];
    }
  }
}

// ---------------- persistent recurrent kernel ----------------
#define SA 948
#define S2 772
__global__ __launch_bounds__(256, 1) void rec_k(
    const float* __restrict__ A1,
    const float* __restrict__ whh1, const float* __restrict__ wih1,
    const float* __restrict__ wih2, const float* __restrict__ whh2,
    const float* __restrict__ bih2, const float* __restrict__ bhh2,
    const float* __restrict__ postw, const float* __restrict__ postb,
    const float* __restrict__ embw,
    float* __restrict__ xbuf, float* __restrict__ h2b,
    unsigned* __restrict__ sy, float* __restrict__ out)
{
  const int wg = blockIdx.x, tid = threadIdx.x;
  const int wv = tid >> 6, l = tid & 63;
  __shared__ float xs[8*SA];     // 30.3 KB staging (stage A largest: 944)
  __shared__ float h2s[8*S2];    // 24.7 KB persistent h2(t-1), b-major planes
  __shared__ float zbuf[96];
  __shared__ float red2[160];

  float wA[15][3];
  float wB[24][3];
  float wC[3][5];
  {
    int Rb = wv*768 + wg*3;
    #pragma unroll
    for (int ki = 0; ki < 15; ++ki){
      int k = l + (ki << 6);
      #pragma unroll
      for (int u = 0; u < 3; ++u){
        float w = 0.f;
        if (k < 768) w = whh1[(Rb + u)*768 + k];
        else if (k < 944) w = wih1[(Rb + u)*944 + k];
        wA[ki][u] = w;
      }
    }
    #pragma unroll
    for (int ki = 0; ki < 24; ++ki){
      int k = l + (ki << 6);
      #pragma unroll
      for (int u = 0; u < 3; ++u)
        wB[ki][u] = (k < 768) ? wih2[(Rb + u)*768 + k] : whh2[(Rb + u)*768 + k - 768];
    }
  }
  if (wg < 88){
    #pragma unroll
    for (int kc = 0; kc < 3; ++kc)
      #pragma unroll
      for (int s = 0; s < 5; ++s)
        wC[kc][s] = postw[(wg*5 + s)*768 + tid + (kc << 8)];
  }
  float b2r = 0.f; int fR = 0, fb = 0;
  if (tid < 96){
    int g = tid / 24, rem = tid - g*24;
    int u = rem >> 3; fb = rem & 7;
    fR = g*768 + wg*3 + u;
    b2r = bih2[fR] + bhh2[fR];
  }
  float pbr = (wg < 88 && tid < 40) ? postb[wg*5 + (tid >> 3)] : 0.f;
  float c1r = 0.f, c2r = 0.f;

  for (int idx = tid; idx < 8*S2; idx += 256) h2s[idx] = 0.f;
  if (wg == 0){
    for (int idx = tid; idx < 1408; idx += 256){
      int e = idx >> 3, bb = idx & 7;
      cstore(&xbuf[(768 + e)*8 + bb], embw[e & 1]);
    }
  }
  unsigned bar = 1;
  gbar(sy, bar, wg);

  for (int t = 0; t < 512; ++t){
    const int cur = t & 1, nxt = cur ^ 1;
    float* xc  = xbuf + cur * 7552;
    float* xn  = xbuf + nxt * 7552;
    float* h2n = h2b + nxt * 6144;

    float a1v = 0.f;
    if (tid < 96) a1v = A1[t*24576 + fR*8 + fb];

    // ---- stage A: gates1 = A1[t] + [h1,emb] @ [whh1|We].T ; cell1 ----
    {
      for (int idx = tid; idx < 3776; idx += 256){
        float a, b; cload64(xc + 2*idx, a, b);
        int k = idx >> 2, p = (idx & 3) << 1;
        xs[p*SA + k]       = a;
        xs[(p + 1)*SA + k] = b;
      }
      __syncthreads();
      float acc[3][8];
      #pragma unroll
      for (int u = 0; u < 3; ++u)
        #pragma unroll
        for (int j = 0; j < 8; ++j) acc[u][j] = 0.f;
      #pragma unroll
      for (int ki = 0; ki < 15; ++ki){
        int k = l + (ki << 6);
        if (k < 944){
          float x0 = xs[k],        x1 = xs[SA + k],   x2 = xs[2*SA + k], x3 = xs[3*SA + k];
          float x4 = xs[4*SA + k], x5 = xs[5*SA + k], x6 = xs[6*SA + k], x7 = xs[7*SA + k];
          #pragma unroll
          for (int u = 0; u < 3; ++u){
            float w = wA[ki][u];
            acc[u][0] = fmaf(w, x0, acc[u][0]);
            acc[u][1] = fmaf(w, x1, acc[u][1]);
            acc[u][2] = fmaf(w, x2, acc[u][2]);
            acc[u][3] = fmaf(w, x3, acc[u][3]);
            acc[u][4] = fmaf(w, x4, acc[u][4]);
            acc[u][5] = fmaf(w, x5, acc[u][5]);
            acc[u][6] = fmaf(w, x6, acc[u][6]);
            acc[u][7] = fmaf(w, x7, acc[u][7]);
          }
        }
      }
      #pragma unroll
      for (int u = 0; u < 3; ++u)
        #pragma unroll
        for (int j = 0; j < 8; ++j){
          float s = acc[u][j];
          s += __shfl_xor(s, 1);  s += __shfl_xor(s, 2);  s += __shfl_xor(s, 4);
          s += __shfl_xor(s, 8);  s += __shfl_xor(s, 16); s += __shfl_xor(s, 32);
          if (l == 0) zbuf[wv*24 + u*8 + j] = s;
        }
      __syncthreads();
      if (tid < 96)
        zbuf[tid] += a1v;
      __syncthreads();
      if (tid < 24){
        float zi = zbuf[tid], zf = zbuf[24 + tid], zg = zbuf[48 + tid], zo = zbuf[72 + tid];
        c1r = sigm(zf)*c1r + sigm(zi)*tanhf(zg);
        float hh = sigm(zo)*tanhf(c1r);
        cstore(&xn[(wg*3 + (tid >> 3))*8 + (tid & 7)], hh);
      }
      ++bar; gbar(sy, bar, wg);
    }

    // ---- stage B: gates2 = h1n @ wih2.T + h2(t-1)[LDS] @ whh2.T + b ----
    {
      for (int idx = tid; idx < 3072; idx += 256){
        float a, b; cload64(xn + 2*idx, a, b);
        int k = idx >> 2, p = (idx & 3) << 1;
        xs[p*S2 + k]       = a;
        xs[(p + 1)*S2 + k] = b;
      }
      __syncthreads();
      float acc[3][8];
      #pragma unroll
      for (int u = 0; u < 3; ++u)
        #pragma unroll
        for (int j = 0; j < 8; ++j) acc[u][j] = 0.f;
      #pragma unroll
      for (int ki = 0; ki < 24; ++ki){
        float x0, x1, x2, x3, x4, x5, x6, x7;
        if (ki < 12){
          int k = l + (ki << 6);
          x0 = xs[k];        x1 = xs[S2 + k];   x2 = xs[2*S2 + k]; x3 = xs[3*S2 + k];
          x4 = xs[4*S2 + k]; x5 = xs[5*S2 + k]; x6 = xs[6*S2 + k]; x7 = xs[7*S2 + k];
        } else {
          int k = l + ((ki - 12) << 6);
          x0 = h2s[k];        x1 = h2s[S2 + k];   x2 = h2s[2*S2 + k]; x3 = h2s[3*S2 + k];
          x4 = h2s[4*S2 + k]; x5 = h2s[5*S2 + k]; x6 = h2s[6*S2 + k]; x7 = h2s[7*S2 + k];
        }
        #pragma unroll
        for (int u = 0; u < 3; ++u){
          float w = wB[ki][u];
          acc[u][0] = fmaf(w, x0, acc[u][0]);
          acc[u][1] = fmaf(w, x1, acc[u][1]);
          acc[u][2] = fmaf(w, x2, acc[u][2]);
          acc[u][3] = fmaf(w, x3, acc[u][3]);
          acc[u][4] = fmaf(w, x4, acc[u][4]);
          acc[u][5] = fmaf(w, x5, acc[u][5]);
          acc[u][6] = fmaf(w, x6, acc[u][6]);
          acc[u][7] = fmaf(w, x7, acc[u][7]);
        }
      }
      #pragma unroll
      for (int u = 0; u < 3; ++u)
        #pragma unroll
        for (int j = 0; j < 8; ++j){
          float s = acc[u][j];
          s += __shfl_xor(s, 1);  s += __shfl_xor(s, 2);  s += __shfl_xor(s, 4);
          s += __shfl_xor(s, 8);  s += __shfl_xor(s, 16); s += __shfl_xor(s, 32);
          if (l == 0) zbuf[wv*24 + u*8 + j] = s;
        }
      __syncthreads();
      if (tid < 96)
        zbuf[tid] += b2r;
      __syncthreads();
      if (tid < 24){
        float zi = zbuf[tid], zf = zbuf[24 + tid], zg = zbuf[48 + tid], zo = zbuf[72 + tid];
        c2r = sigm(zf)*c2r + sigm(zi)*tanhf(zg);
        float hh = sigm(zo)*tanhf(c2r);
        cstore(&h2n[(wg*3 + (tid >> 3))*8 + (tid & 7)], hh);
      }
      ++bar; gbar(sy, bar, wg);
    }

    // ---- stage C: ALL WGs stage h2n into h2s; wg<88 logits+argmax+emb ----
    {
      for (int idx = tid; idx < 3072; idx += 256){
        float a, b; cload64(h2n + 2*idx, a, b);
        int k = idx >> 2, p = (idx & 3) << 1;
        h2s[p*S2 + k]       = a;
        h2s[(p + 1)*S2 + k] = b;
      }
      __syncthreads();
      if (wg < 88){
        float acc[5][8];
        #pragma unroll
        for (int s = 0; s < 5; ++s)
          #pragma unroll
          for (int j = 0; j < 8; ++j) acc[s][j] = 0.f;
        #pragma unroll
        for (int kc = 0; kc < 3; ++kc){
          int k = tid + (kc << 8);
          float x0 = h2s[k],        x1 = h2s[S2 + k],   x2 = h2s[2*S2 + k], x3 = h2s[3*S2 + k];
          float x4 = h2s[4*S2 + k], x5 = h2s[5*S2 + k], x6 = h2s[6*S2 + k], x7 = h2s[7*S2 + k];
          #pragma unroll
          for (int s = 0; s < 5; ++s){
            float w = wC[kc][s];
            acc[s][0] = fmaf(w, x0, acc[s][0]);
            acc[s][1] = fmaf(w, x1, acc[s][1]);
            acc[s][2] = fmaf(w, x2, acc[s][2]);
            acc[s][3] = fmaf(w, x3, acc[s][3]);
            acc[s][4] = fmaf(w, x4, acc[s][4]);
            acc[s][5] = fmaf(w, x5, acc[s][5]);
            acc[s][6] = fmaf(w, x6, acc[s][6]);
            acc[s][7] = fmaf(w, x7, acc[s][7]);
          }
        }
        #pragma unroll
        for (int s = 0; s < 5; ++s)
          #pragma unroll
          for (int j = 0; j < 8; ++j){
            float v = acc[s][j];
            v += __shfl_xor(v, 1);  v += __shfl_xor(v, 2);  v += __shfl_xor(v, 4);
            v += __shfl_xor(v, 8);  v += __shfl_xor(v, 16); v += __shfl_xor(v, 32);
            if (l == 0) red2[(s*8 + j)*4 + wv] = v;
          }
        __syncthreads();
        if (tid < 40){
          float sum = red2[tid*4] + red2[tid*4 + 1] + red2[tid*4 + 2] + red2[tid*4 + 3] + pbr;
          int s = tid >> 3, bb = tid & 7;
          out[bb*225280 + t*440 + wg*5 + s] = sum;
          zbuf[tid] = sum;
        }
        __syncthreads();
        if (tid < 8){
          float best = zbuf[tid]; int bs = 0;
          #pragma unroll
          for (int s = 1; s < 5; ++s){
            float v = zbuf[s*8 + tid];
            if (v > best){ best = v; bs = s; }   // first max wins (jnp.argmax)
          }
          cstore(&xn[(768 + wg*2)*8 + tid],     embw[bs*2]);
          cstore(&xn[(768 + wg*2 + 1)*8 + tid], embw[bs*2 + 1]);
        }
      }
      ++bar; gbar(sy, bar, wg);
    }
  }
}

extern "C" void kernel_launch(void* const* d_in, const int* in_sizes, int n_in,
                              void* d_out, int out_size, void* d_ws, size_t ws_size,
                              hipStream_t stream)
{
  (void)in_sizes; (void)n_in; (void)out_size; (void)ws_size;
  const float* mel  = (const float*)d_in[0];
  const float* w1   = (const float*)d_in[1];
  const float* b1   = (const float*)d_in[2];
  const float* g1   = (const float*)d_in[3];
  const float* be1  = (const float*)d_in[4];
  const float* m1   = (const float*)d_in[5];
  const float* v1   = (const float*)d_in[6];
  const float* w2   = (const float*)d_in[7];
  const float* b2   = (const float*)d_in[8];
  const float* g2   = (const float*)d_in[9];
  const float* be2  = (const float*)d_in[10];
  const float* m2   = (const float*)d_in[11];
  const float* v2   = (const float*)d_in[12];
  const float* w3   = (const float*)d_in[13];
  const float* b3   = (const float*)d_in[14];
  const float* g3   = (const float*)d_in[15];
  const float* be3  = (const float*)d_in[16];
  const float* m3   = (const float*)d_in[17];
  const float* v3   = (const float*)d_in[18];
  const float* fcw  = (const float*)d_in[19];
  const float* fcb  = (const float*)d_in[20];
  const float* wih1 = (const float*)d_in[21];
  const float* whh1 = (const float*)d_in[22];
  const float* bih1 = (const float*)d_in[23];
  const float* bhh1 = (const float*)d_in[24];
  const float* wih2 = (const float*)d_in[25];
  const float* whh2 = (const float*)d_in[26];
  const float* bih2 = (const float*)d_in[27];
  const float* bhh2 = (const float*)d_in[28];
  const float* postw= (const float*)d_in[29];
  const float* postb= (const float*)d_in[30];
  const float* embw = (const float*)d_in[31];

  float* ws    = (float*)d_ws;
  float* c3p   = ws + WS_C3;
  float* c2ch  = ws + WS_C2CH;
  float* ac    = ws + WS_AC;
  float* A1    = ws + WS_A1;
  float* st    = ws + WS_ST;
  float* xbuf  = st;
  float* h2b   = st + 15104;
  unsigned* sy = (unsigned*)(st + 27392);
  float* outp  = (float*)d_out;

  // zero recurrent state + barrier slots/flags (27392 floats + 8208 u32)
  hipMemsetAsync(st, 0, 35600 * sizeof(float), stream);

  for (int c = 0; c < 4; ++c){
    int t0 = c * 128;
    conv2f_k<<<dim3(8*130), dim3(256), 0, stream>>>(
        mel, w1, b1, g1, be1, m1, v1, w2, b2, g2, be2, m2, v2, c2ch, t0);
    conv3_k<<<dim3(8*128), dim3(256), 0, stream>>>(
        c2ch, w3, b3, g3, be3, m3, v3, c3p, t0);
  }
  gemm_fc_k<<<dim3(32, 6), dim3(256), 0, stream>>>(c3p, fcw, fcb, ac);
  gemm_a1_k<<<dim3(32, 24), dim3(256), 0, stream>>>(ac, wih1, bih1, bhh1, A1);

  rec_k<<<dim3(256), dim3(256), 0, stream>>>(
      A1, whh1, wih1, wih2, whh2, bih2, bhh2, postw, postb, embw,
      xbuf, h2b, sy, outp);
}